// Round 11
// baseline (192.138 us; speedup 1.0000x reference)
//
#include <hip/hip_runtime.h>
#include <hip/hip_bf16.h>

// Attention B=4,N=2048,D=384,H=8,DH=48 — Round 10:
//  - attn: 64 queries per wave (block=128 thr, 2 waves), TQ=128, grid 512.
//    Halves per-block K/V LDS fragment reads (LDS-instr-bound per R9 model).
//  - qkv (V LDS-transpose epilogue) / proj / prep unchanged from R9.

typedef _Float16 f16x8 __attribute__((ext_vector_type(8)));
typedef _Float16 f16x4 __attribute__((ext_vector_type(4)));
typedef float    f32x4 __attribute__((ext_vector_type(4)));
typedef float    f32x16 __attribute__((ext_vector_type(16)));

// scale * log2(e) = 48^-0.5 * 1.4426950408889634
#define QSCL 0.20822035963448658f

// ---------------------------------------------------------------------------
// prep: LDS-tiled coalesced weight transposes (Wqkv^T, Wproj^T) -> f16 [n][k]
// ---------------------------------------------------------------------------
__global__ __launch_bounds__(256) void prep(const float* __restrict__ wq,
                                            const float* __restrict__ wp,
                                            _Float16* __restrict__ wqt,
                                            _Float16* __restrict__ wpt)
{
    __shared__ _Float16 t[64][65];
    const int blk = blockIdx.x, tid = threadIdx.x;
    const float* src; _Float16* dst; int Nn, k0, n0;
    if (blk < 108) {            // Wqkv: 6 k-tiles x 18 n-tiles
        src = wq; dst = wqt; Nn = 1152;
        k0 = (blk % 6) * 64; n0 = (blk / 6) * 64;
    } else {                    // Wproj: 6 x 6
        const int b2 = blk - 108;
        src = wp; dst = wpt; Nn = 384;
        k0 = (b2 % 6) * 64; n0 = (b2 / 6) * 64;
    }
    #pragma unroll
    for (int i = 0; i < 16; i++) {
        const int id = tid + i * 256;            // 0..4095
        const int k = id >> 6, n = id & 63;      // coalesced over n
        t[k][n] = (_Float16)src[(size_t)(k0 + k) * Nn + n0 + n];
    }
    __syncthreads();
    #pragma unroll
    for (int i = 0; i < 16; i++) {
        const int id = tid + i * 256;
        const int n = id >> 6, k = id & 63;      // coalesced over k
        dst[(size_t)(n0 + n) * 384 + k0 + k] = t[k][n];
    }
}

// ---------------------------------------------------------------------------
// QKV GEMM: A = x[8192][384] fp32 (cvt at staging), Bt = wqkvt[1152][384] f16.
// 128x64 tile, BK=64, padded LDS, 16x16x32 MFMA, 4 waves, reg-prefetch.
// s==2 (V) blocks: epilogue via LDS transpose -> coalesced b128 stores.
// ---------------------------------------------------------------------------
union QkvSmem {
    struct { _Float16 As[128][72]; _Float16 Bs[64][72]; } g;  // 27648 B
    _Float16 Ts[64][136];   // transpose buffer [col][n] 17408 B (aliases As)
};

__global__ __launch_bounds__(256) void qkv_f16(const float* __restrict__ X,
                                               const _Float16* __restrict__ Bt,
                                               _Float16* __restrict__ qh,
                                               _Float16* __restrict__ kh,
                                               _Float16* __restrict__ vt)
{
    __shared__ QkvSmem sm;
    const int tid = threadIdx.x;
    const int w = tid >> 6, lane = tid & 63, cl = lane & 15, quad = lane >> 4;
    const int bm = blockIdx.x, bn = blockIdx.y;

    f32x4 acc[2][4];
    const f32x4 z4 = {0.f, 0.f, 0.f, 0.f};
    #pragma unroll
    for (int mi = 0; mi < 2; mi++)
        #pragma unroll
        for (int t = 0; t < 4; t++) acc[mi][t] = z4;

    const int ar = tid >> 3, ac = (tid & 7) * 8;
    const float*    Ag = X  + (size_t)(bm * 128 + ar) * 384 + ac;
    const _Float16* Bg = Bt + (size_t)(bn * 64  + ar) * 384 + ac;

    float4 pa0[4], pa1[4];
    f16x8 pb[2];
    #pragma unroll
    for (int j = 0; j < 4; j++) {
        pa0[j] = *(const float4*)(Ag + (size_t)(32 * j) * 384);
        pa1[j] = *(const float4*)(Ag + (size_t)(32 * j) * 384 + 4);
    }
    #pragma unroll
    for (int j = 0; j < 2; j++) pb[j] = *(const f16x8*)(Bg + (size_t)(32 * j) * 384);

    for (int k0 = 0; k0 < 384; k0 += 64) {
        __syncthreads();
        #pragma unroll
        for (int j = 0; j < 4; j++) {
            f16x8 hh;
            hh[0] = (_Float16)pa0[j].x; hh[1] = (_Float16)pa0[j].y;
            hh[2] = (_Float16)pa0[j].z; hh[3] = (_Float16)pa0[j].w;
            hh[4] = (_Float16)pa1[j].x; hh[5] = (_Float16)pa1[j].y;
            hh[6] = (_Float16)pa1[j].z; hh[7] = (_Float16)pa1[j].w;
            *(f16x8*)&sm.g.As[ar + 32 * j][ac] = hh;
        }
        #pragma unroll
        for (int j = 0; j < 2; j++) *(f16x8*)&sm.g.Bs[ar + 32 * j][ac] = pb[j];
        __syncthreads();
        if (k0 + 64 < 384) {
            #pragma unroll
            for (int j = 0; j < 4; j++) {
                pa0[j] = *(const float4*)(Ag + (size_t)(32 * j) * 384 + k0 + 64);
                pa1[j] = *(const float4*)(Ag + (size_t)(32 * j) * 384 + k0 + 68);
            }
            #pragma unroll
            for (int j = 0; j < 2; j++)
                pb[j] = *(const f16x8*)(Bg + (size_t)(32 * j) * 384 + k0 + 64);
        }
        #pragma unroll
        for (int kh2 = 0; kh2 < 2; kh2++) {
            f16x8 bf[4];
            #pragma unroll
            for (int t = 0; t < 4; t++)
                bf[t] = *(const f16x8*)&sm.g.Bs[t * 16 + cl][kh2 * 32 + quad * 8];
            #pragma unroll
            for (int mi = 0; mi < 2; mi++) {
                const f16x8 af = *(const f16x8*)&sm.g.As[w * 32 + mi * 16 + cl][kh2 * 32 + quad * 8];
                #pragma unroll
                for (int t = 0; t < 4; t++)
                    acc[mi][t] = __builtin_amdgcn_mfma_f32_16x16x32_f16(af, bf[t], acc[mi][t], 0, 0, 0);
            }
        }
    }

    const int s = (bn * 64) / 384;    // uniform per block
    if (s == 2) {
        // ---- V: LDS transpose -> coalesced stores along n ----
        __syncthreads();              // all fragment reads done
        #pragma unroll
        for (int t = 0; t < 4; t++)
            #pragma unroll
            for (int mi = 0; mi < 2; mi++)
                #pragma unroll
                for (int r = 0; r < 4; r++)
                    sm.Ts[t * 16 + cl][w * 32 + mi * 16 + quad * 4 + r] =
                        (_Float16)acc[mi][t][r];
        __syncthreads();
        const int colbase = bn * 64 - 768;       // 0..320
        const int b  = (bm * 128) >> 11;         // constant per block
        const int n0 = (bm * 128) & 2047;
        #pragma unroll
        for (int i = 0; i < 4; i++) {
            const int c = i * 256 + tid;         // 0..1023 chunks of 8
            const int col = c >> 4, nc = c & 15;
            const int gcol = colbase + col;
            const int head = gcol / 48, d = gcol - head * 48;
            const int bh = b * 8 + head;
            *(f16x8*)&vt[(size_t)(bh * 48 + d) * 2048 + n0 + nc * 8] =
                *(const f16x8*)&sm.Ts[col][nc * 8];
        }
    } else {
        #pragma unroll
        for (int t = 0; t < 4; t++) {
            const int col  = bn * 64 + t * 16 + cl - s * 384;  // 0..383
            const int head = col / 48, d = col - head * 48;
            #pragma unroll
            for (int mi = 0; mi < 2; mi++) {
                #pragma unroll
                for (int r = 0; r < 4; r++) {
                    const int row = bm * 128 + w * 32 + mi * 16 + quad * 4 + r;
                    const int b = row >> 11, n = row & 2047;
                    const int bh = b * 8 + head;
                    const float v = acc[mi][t][r];
                    if (s == 0)
                        qh[(size_t)(bh * 2048 + n) * 48 + d] = (_Float16)(v * QSCL);
                    else
                        kh[(size_t)(bh * 2048 + n) * 48 + d] = (_Float16)v;
                }
            }
        }
    }
}

// ---------------------------------------------------------------------------
// Flash attention, 32x32x16 f16 MFMA, no-max softmax.
// Block 128 = 2 waves; each wave owns 64 queries (2 query-groups of 32);
// TQ=128 per block, 64-key tiles, full keys per wave.
// S^T = K.Q^T (A=K-frag shared across qg); P -> Ps (wave-private rows, b64);
// PV: A=Ps rows, B=Vts; l via ones-row 48 of V^T. Reg-prefetch staging.
// ---------------------------------------------------------------------------
__global__ __launch_bounds__(128, 1) void attn_f16(const _Float16* __restrict__ qh,
                                                   const _Float16* __restrict__ kh,
                                                   const _Float16* __restrict__ vt,
                                                   _Float16* __restrict__ ab)
{
    __shared__ _Float16 Ks[64][56];    // [key][dh]    7 KB
    __shared__ _Float16 Vts[64][72];   // [dh][key]    9 KB; row 48 ones, 49-63 zero
    __shared__ _Float16 Ps[128][72];   // [query][key] 18 KB
    const int tid = threadIdx.x;
    const int wq = tid >> 6, lane = tid & 63, ln = lane & 31, h = lane >> 5;
    const int bh = blockIdx.x, qt = blockIdx.y;

    // one-time: Vts rows 48..63 (48 = ones for l, rest zero)
    for (int i = tid; i < 16 * 72; i += 128) {
        const int r = 48 + i / 72, c = i - (i / 72) * 72;
        Vts[r][c] = (r == 48) ? (_Float16)1.0f : (_Float16)0.0f;
    }

    // Q B-frags: query = qt*128 + wq*64 + qg*32 + ln, dh = 16i + 8h + 0..7
    f16x8 qf[2][3];
    #pragma unroll
    for (int qg = 0; qg < 2; qg++) {
        const _Float16* qp = qh + (size_t)(bh * 2048 + qt * 128 + wq * 64 + qg * 32 + ln) * 48 + 8 * h;
        qf[qg][0] = *(const f16x8*)qp;
        qf[qg][1] = *(const f16x8*)(qp + 16);
        qf[qg][2] = *(const f16x8*)(qp + 32);
    }

    f32x16 o[2][2];
    #pragma unroll
    for (int qg = 0; qg < 2; qg++)
        #pragma unroll
        for (int cg = 0; cg < 2; cg++)
            #pragma unroll
            for (int r = 0; r < 16; r++) o[qg][cg][r] = 0.f;

    const _Float16* kbase = kh + (size_t)bh * 2048 * 48;
    const _Float16* vbase = vt + (size_t)bh * 48 * 2048;

    // staging: K 384 chunks (row=c/6, col=(c%6)*8); V 384 (row=c>>3, col=(c&7)*8)
    int krow[3], kcol[3], vrow[3];
    const _Float16 *ksp[3], *vsp[3];
    const int vcol = (tid & 7) * 8;    // (tid+128j)&7 == tid&7
    #pragma unroll
    for (int j = 0; j < 3; j++) {
        const int c = tid + 128 * j;
        krow[j] = c / 6;  kcol[j] = (c % 6) * 8;
        vrow[j] = c >> 3;
        ksp[j] = kbase + (size_t)krow[j] * 48 + kcol[j];
        vsp[j] = vbase + (size_t)vrow[j] * 2048 + vcol;
    }
    f16x8 rk[3], rv[3];
    #pragma unroll
    for (int j = 0; j < 3; j++) { rk[j] = *(const f16x8*)ksp[j]; rv[j] = *(const f16x8*)vsp[j]; }

    for (int kt = 0; kt < 2048; kt += 64) {
        __syncthreads();
        #pragma unroll
        for (int j = 0; j < 3; j++) {
            *(f16x8*)&Ks[krow[j]][kcol[j]] = rk[j];
            *(f16x8*)&Vts[vrow[j]][vcol]   = rv[j];
        }
        __syncthreads();
        if (kt + 64 < 2048) {
            #pragma unroll
            for (int j = 0; j < 3; j++) {
                rk[j] = *(const f16x8*)(ksp[j] + (size_t)(kt + 64) * 48);
                rv[j] = *(const f16x8*)(vsp[j] + kt + 64);
            }
        }

        // ---- S^T = K.Q^T per key-group; P = exp2(S^T) -> Ps ----
        #pragma unroll
        for (int kg = 0; kg < 2; kg++) {
            f32x16 s0, s1;
            #pragma unroll
            for (int r = 0; r < 16; r++) { s0[r] = 0.f; s1[r] = 0.f; }
            #pragma unroll
            for (int i = 0; i < 3; i++) {
                const f16x8 ka = *(const f16x8*)&Ks[kg * 32 + ln][16 * i + 8 * h];
                s0 = __builtin_amdgcn_mfma_f32_32x32x16_f16(ka, qf[0][i], s0, 0, 0, 0);
                s1 = __builtin_amdgcn_mfma_f32_32x32x16_f16(ka, qf[1][i], s1, 0, 0, 0);
            }
            #pragma unroll
            for (int q = 0; q < 4; q++) {
                f16x4 pk;
                pk[0] = (_Float16)exp2f(s0[4 * q + 0]);
                pk[1] = (_Float16)exp2f(s0[4 * q + 1]);
                pk[2] = (_Float16)exp2f(s0[4 * q + 2]);
                pk[3] = (_Float16)exp2f(s0[4 * q + 3]);
                *(f16x4*)&Ps[wq * 64 + ln][kg * 32 + 8 * q + 4 * h] = pk;
                f16x4 pk1;
                pk1[0] = (_Float16)exp2f(s1[4 * q + 0]);
                pk1[1] = (_Float16)exp2f(s1[4 * q + 1]);
                pk1[2] = (_Float16)exp2f(s1[4 * q + 2]);
                pk1[3] = (_Float16)exp2f(s1[4 * q + 3]);
                *(f16x4*)&Ps[wq * 64 + 32 + ln][kg * 32 + 8 * q + 4 * h] = pk1;
            }
        }

        // ---- O += P.V : 4 K=16 chunks x 2 qg x 2 cg ----
        #pragma unroll
        for (int c = 0; c < 4; c++) {
            const f16x8 pa0 = *(const f16x8*)&Ps[wq * 64 + ln][16 * c + 8 * h];
            const f16x8 pa1 = *(const f16x8*)&Ps[wq * 64 + 32 + ln][16 * c + 8 * h];
            const f16x8 bv0 = *(const f16x8*)&Vts[ln][16 * c + 8 * h];
            const f16x8 bv1 = *(const f16x8*)&Vts[32 + ln][16 * c + 8 * h];
            o[0][0] = __builtin_amdgcn_mfma_f32_32x32x16_f16(pa0, bv0, o[0][0], 0, 0, 0);
            o[0][1] = __builtin_amdgcn_mfma_f32_32x32x16_f16(pa0, bv1, o[0][1], 0, 0, 0);
            o[1][0] = __builtin_amdgcn_mfma_f32_32x32x16_f16(pa1, bv0, o[1][0], 0, 0, 0);
            o[1][1] = __builtin_amdgcn_mfma_f32_32x32x16_f16(pa1, bv1, o[1][1], 0, 0, 0);
        }
    }

    // ---- normalize + store. l = O col 48 = cg1 col 16 -> lane h*32+16 ----
    const int b = bh >> 3, hd = bh & 7;
    #pragma unroll
    for (int qg = 0; qg < 2; qg++) {
        #pragma unroll
        for (int r = 0; r < 16; r++) {
            const float lr = __shfl(o[qg][1][r], (lane & 32) + 16);
            const float inv = 1.f / lr;
            const int q = qt * 128 + wq * 64 + qg * 32 + (r & 3) + 8 * (r >> 2) + 4 * h;
            _Float16* orow = ab + (size_t)(b * 2048 + q) * 384 + hd * 48;
            orow[ln] = (_Float16)(o[qg][0][r] * inv);
            if (ln < 16) orow[32 + ln] = (_Float16)(o[qg][1][r] * inv);
        }
    }
}

// ---------------------------------------------------------------------------
// Proj GEMM: A = ab[8192][384] f16, Bt = wprojt[384][384] f16, +bias -> fp32
// 64x64 tile, BK=64, padded LDS, reg-prefetch.
// ---------------------------------------------------------------------------
__global__ __launch_bounds__(256) void proj_f16(const _Float16* __restrict__ A,
                                                const _Float16* __restrict__ Bt,
                                                const float* __restrict__ bias,
                                                float* __restrict__ out)
{
    __shared__ _Float16 As[64][72];
    __shared__ _Float16 Bs[64][72];
    const int tid = threadIdx.x;
    const int w = tid >> 6, lane = tid & 63, cl = lane & 15, quad = lane >> 4;
    const int bm = blockIdx.x, bn = blockIdx.y;

    f32x4 acc[4];
    const f32x4 z4 = {0.f, 0.f, 0.f, 0.f};
    #pragma unroll
    for (int t = 0; t < 4; t++) acc[t] = z4;

    const int ar = tid >> 3, ac = (tid & 7) * 8;
    const _Float16* Ag = A  + (size_t)(bm * 64 + ar) * 384 + ac;
    const _Float16* Bg = Bt + (size_t)(bn * 64 + ar) * 384 + ac;

    f16x8 pa[2], pb[2];
    #pragma unroll
    for (int j = 0; j < 2; j++) {
        pa[j] = *(const f16x8*)(Ag + (size_t)(32 * j) * 384);
        pb[j] = *(const f16x8*)(Bg + (size_t)(32 * j) * 384);
    }

    for (int k0 = 0; k0 < 384; k0 += 64) {
        __syncthreads();
        #pragma unroll
        for (int j = 0; j < 2; j++) {
            *(f16x8*)&As[ar + 32 * j][ac] = pa[j];
            *(f16x8*)&Bs[ar + 32 * j][ac] = pb[j];
        }
        __syncthreads();
        if (k0 + 64 < 384) {
            #pragma unroll
            for (int j = 0; j < 2; j++) {
                pa[j] = *(const f16x8*)(Ag + (size_t)(32 * j) * 384 + k0 + 64);
                pb[j] = *(const f16x8*)(Bg + (size_t)(32 * j) * 384 + k0 + 64);
            }
        }
        #pragma unroll
        for (int kh2 = 0; kh2 < 2; kh2++) {
            const f16x8 af = *(const f16x8*)&As[w * 16 + cl][kh2 * 32 + quad * 8];
            #pragma unroll
            for (int t = 0; t < 4; t++) {
                const f16x8 bf = *(const f16x8*)&Bs[t * 16 + cl][kh2 * 32 + quad * 8];
                acc[t] = __builtin_amdgcn_mfma_f32_16x16x32_f16(af, bf, acc[t], 0, 0, 0);
            }
        }
    }

    #pragma unroll
    for (int t = 0; t < 4; t++) {
        const int col = bn * 64 + t * 16 + cl;
        const float bv = bias[col];
        #pragma unroll
        for (int r = 0; r < 4; r++) {
            const int row = bm * 64 + w * 16 + quad * 4 + r;
            out[(size_t)row * 384 + col] = acc[t][r] + bv;
        }
    }
}

// ---------------------------------------------------------------------------
extern "C" void kernel_launch(void* const* d_in, const int* in_sizes, int n_in,
                              void* d_out, int out_size, void* d_ws, size_t ws_size,
                              hipStream_t stream) {
    const float* x     = (const float*)d_in[0];  // [4,2048,384]
    const float* Wqkv  = (const float*)d_in[1];  // [384,1152]
    const float* Wproj = (const float*)d_in[2];  // [384,384]
    const float* bproj = (const float*)d_in[3];  // [384]
    float* out = (float*)d_out;

    char* ws = (char*)d_ws;
    _Float16* wqkvt  = (_Float16*)(ws + 0);          // 1152*384*2 =   884,736
    _Float16* wprojt = (_Float16*)(ws + 884736);     // 384*384*2  =   294,912
    _Float16* qh     = (_Float16*)(ws + 1179648);    // 32*2048*48*2 = 6,291,456
    _Float16* kh     = (_Float16*)(ws + 7471104);    // 6,291,456
    _Float16* vt     = (_Float16*)(ws + 13762560);   // 6,291,456
    _Float16* ab     = (_Float16*)(ws + 20054016);   // 6,291,456
    // total 26,345,472 B

    prep<<<144, 256, 0, stream>>>(Wqkv, Wproj, wqkvt, wprojt);
    qkv_f16<<<dim3(64, 18), 256, 0, stream>>>(x, wqkvt, qh, kh, vt);
    attn_f16<<<dim3(32, 16), 128, 0, stream>>>(qh, kh, vt, ab);
    proj_f16<<<dim3(128, 6), 256, 0, stream>>>(ab, wprojt, bproj, out);
}

// Round 12
// 162.478 us; speedup vs baseline: 1.1825x; 1.1825x over previous
//
#include <hip/hip_runtime.h>
#include <hip/hip_bf16.h>

// Attention B=4,N=2048,D=384,H=8,DH=48 — Round 11:
//  - attn: R9 per-wave structure (32 queries/wave, full 64-key tiles) but
//    TQ=64, block=128 (2 waves) -> grid 1024 = 4 independent barrier domains
//    per CU (was 2). Same 8 waves/CU; staging barriers decorrelate.
//  - qkv (V LDS-transpose epilogue) / proj / prep unchanged from R9.

typedef _Float16 f16x8 __attribute__((ext_vector_type(8)));
typedef _Float16 f16x4 __attribute__((ext_vector_type(4)));
typedef float    f32x4 __attribute__((ext_vector_type(4)));
typedef float    f32x16 __attribute__((ext_vector_type(16)));

// scale * log2(e) = 48^-0.5 * 1.4426950408889634
#define QSCL 0.20822035963448658f

// ---------------------------------------------------------------------------
// prep: LDS-tiled coalesced weight transposes (Wqkv^T, Wproj^T) -> f16 [n][k]
// ---------------------------------------------------------------------------
__global__ __launch_bounds__(256) void prep(const float* __restrict__ wq,
                                            const float* __restrict__ wp,
                                            _Float16* __restrict__ wqt,
                                            _Float16* __restrict__ wpt)
{
    __shared__ _Float16 t[64][65];
    const int blk = blockIdx.x, tid = threadIdx.x;
    const float* src; _Float16* dst; int Nn, k0, n0;
    if (blk < 108) {            // Wqkv: 6 k-tiles x 18 n-tiles
        src = wq; dst = wqt; Nn = 1152;
        k0 = (blk % 6) * 64; n0 = (blk / 6) * 64;
    } else {                    // Wproj: 6 x 6
        const int b2 = blk - 108;
        src = wp; dst = wpt; Nn = 384;
        k0 = (b2 % 6) * 64; n0 = (b2 / 6) * 64;
    }
    #pragma unroll
    for (int i = 0; i < 16; i++) {
        const int id = tid + i * 256;            // 0..4095
        const int k = id >> 6, n = id & 63;      // coalesced over n
        t[k][n] = (_Float16)src[(size_t)(k0 + k) * Nn + n0 + n];
    }
    __syncthreads();
    #pragma unroll
    for (int i = 0; i < 16; i++) {
        const int id = tid + i * 256;
        const int n = id >> 6, k = id & 63;      // coalesced over k
        dst[(size_t)(n0 + n) * 384 + k0 + k] = t[k][n];
    }
}

// ---------------------------------------------------------------------------
// QKV GEMM: A = x[8192][384] fp32 (cvt at staging), Bt = wqkvt[1152][384] f16.
// 128x64 tile, BK=64, padded LDS, 16x16x32 MFMA, 4 waves, reg-prefetch.
// s==2 (V) blocks: epilogue via LDS transpose -> coalesced b128 stores.
// ---------------------------------------------------------------------------
union QkvSmem {
    struct { _Float16 As[128][72]; _Float16 Bs[64][72]; } g;  // 27648 B
    _Float16 Ts[64][136];   // transpose buffer [col][n] 17408 B (aliases As)
};

__global__ __launch_bounds__(256) void qkv_f16(const float* __restrict__ X,
                                               const _Float16* __restrict__ Bt,
                                               _Float16* __restrict__ qh,
                                               _Float16* __restrict__ kh,
                                               _Float16* __restrict__ vt)
{
    __shared__ QkvSmem sm;
    const int tid = threadIdx.x;
    const int w = tid >> 6, lane = tid & 63, cl = lane & 15, quad = lane >> 4;
    const int bm = blockIdx.x, bn = blockIdx.y;

    f32x4 acc[2][4];
    const f32x4 z4 = {0.f, 0.f, 0.f, 0.f};
    #pragma unroll
    for (int mi = 0; mi < 2; mi++)
        #pragma unroll
        for (int t = 0; t < 4; t++) acc[mi][t] = z4;

    const int ar = tid >> 3, ac = (tid & 7) * 8;
    const float*    Ag = X  + (size_t)(bm * 128 + ar) * 384 + ac;
    const _Float16* Bg = Bt + (size_t)(bn * 64  + ar) * 384 + ac;

    float4 pa0[4], pa1[4];
    f16x8 pb[2];
    #pragma unroll
    for (int j = 0; j < 4; j++) {
        pa0[j] = *(const float4*)(Ag + (size_t)(32 * j) * 384);
        pa1[j] = *(const float4*)(Ag + (size_t)(32 * j) * 384 + 4);
    }
    #pragma unroll
    for (int j = 0; j < 2; j++) pb[j] = *(const f16x8*)(Bg + (size_t)(32 * j) * 384);

    for (int k0 = 0; k0 < 384; k0 += 64) {
        __syncthreads();
        #pragma unroll
        for (int j = 0; j < 4; j++) {
            f16x8 hh;
            hh[0] = (_Float16)pa0[j].x; hh[1] = (_Float16)pa0[j].y;
            hh[2] = (_Float16)pa0[j].z; hh[3] = (_Float16)pa0[j].w;
            hh[4] = (_Float16)pa1[j].x; hh[5] = (_Float16)pa1[j].y;
            hh[6] = (_Float16)pa1[j].z; hh[7] = (_Float16)pa1[j].w;
            *(f16x8*)&sm.g.As[ar + 32 * j][ac] = hh;
        }
        #pragma unroll
        for (int j = 0; j < 2; j++) *(f16x8*)&sm.g.Bs[ar + 32 * j][ac] = pb[j];
        __syncthreads();
        if (k0 + 64 < 384) {
            #pragma unroll
            for (int j = 0; j < 4; j++) {
                pa0[j] = *(const float4*)(Ag + (size_t)(32 * j) * 384 + k0 + 64);
                pa1[j] = *(const float4*)(Ag + (size_t)(32 * j) * 384 + k0 + 68);
            }
            #pragma unroll
            for (int j = 0; j < 2; j++)
                pb[j] = *(const f16x8*)(Bg + (size_t)(32 * j) * 384 + k0 + 64);
        }
        #pragma unroll
        for (int kh2 = 0; kh2 < 2; kh2++) {
            f16x8 bf[4];
            #pragma unroll
            for (int t = 0; t < 4; t++)
                bf[t] = *(const f16x8*)&sm.g.Bs[t * 16 + cl][kh2 * 32 + quad * 8];
            #pragma unroll
            for (int mi = 0; mi < 2; mi++) {
                const f16x8 af = *(const f16x8*)&sm.g.As[w * 32 + mi * 16 + cl][kh2 * 32 + quad * 8];
                #pragma unroll
                for (int t = 0; t < 4; t++)
                    acc[mi][t] = __builtin_amdgcn_mfma_f32_16x16x32_f16(af, bf[t], acc[mi][t], 0, 0, 0);
            }
        }
    }

    const int s = (bn * 64) / 384;    // uniform per block
    if (s == 2) {
        // ---- V: LDS transpose -> coalesced stores along n ----
        __syncthreads();              // all fragment reads done
        #pragma unroll
        for (int t = 0; t < 4; t++)
            #pragma unroll
            for (int mi = 0; mi < 2; mi++)
                #pragma unroll
                for (int r = 0; r < 4; r++)
                    sm.Ts[t * 16 + cl][w * 32 + mi * 16 + quad * 4 + r] =
                        (_Float16)acc[mi][t][r];
        __syncthreads();
        const int colbase = bn * 64 - 768;       // 0..320
        const int b  = (bm * 128) >> 11;         // constant per block
        const int n0 = (bm * 128) & 2047;
        #pragma unroll
        for (int i = 0; i < 4; i++) {
            const int c = i * 256 + tid;         // 0..1023 chunks of 8
            const int col = c >> 4, nc = c & 15;
            const int gcol = colbase + col;
            const int head = gcol / 48, d = gcol - head * 48;
            const int bh = b * 8 + head;
            *(f16x8*)&vt[(size_t)(bh * 48 + d) * 2048 + n0 + nc * 8] =
                *(const f16x8*)&sm.Ts[col][nc * 8];
        }
    } else {
        #pragma unroll
        for (int t = 0; t < 4; t++) {
            const int col  = bn * 64 + t * 16 + cl - s * 384;  // 0..383
            const int head = col / 48, d = col - head * 48;
            #pragma unroll
            for (int mi = 0; mi < 2; mi++) {
                #pragma unroll
                for (int r = 0; r < 4; r++) {
                    const int row = bm * 128 + w * 32 + mi * 16 + quad * 4 + r;
                    const int b = row >> 11, n = row & 2047;
                    const int bh = b * 8 + head;
                    const float v = acc[mi][t][r];
                    if (s == 0)
                        qh[(size_t)(bh * 2048 + n) * 48 + d] = (_Float16)(v * QSCL);
                    else
                        kh[(size_t)(bh * 2048 + n) * 48 + d] = (_Float16)v;
                }
            }
        }
    }
}

// ---------------------------------------------------------------------------
// Flash attention, 32x32x16 f16 MFMA, no-max softmax.
// Block 128 = 2 waves; each wave owns 32 queries over full 64-key tiles
// (identical per-wave work to R9). TQ=64, grid (32,32)=1024 -> 4 blocks/CU,
// 4 independent barrier domains. Reg-prefetch staging; l via ones-row 48.
// ---------------------------------------------------------------------------
__global__ __launch_bounds__(128, 2) void attn_f16(const _Float16* __restrict__ qh,
                                                   const _Float16* __restrict__ kh,
                                                   const _Float16* __restrict__ vt,
                                                   _Float16* __restrict__ ab)
{
    __shared__ _Float16 Ks[64][56];    // [key][dh]    7168 B
    __shared__ _Float16 Vts[64][72];   // [dh][key]    9216 B; row 48 ones, 49-63 zero
    __shared__ _Float16 Ps[64][72];    // [query][key] 9216 B
    const int tid = threadIdx.x;
    const int wq = tid >> 6, lane = tid & 63, ln = lane & 31, h = lane >> 5;
    const int bh = blockIdx.x, qt = blockIdx.y;

    // one-time: Vts rows 48..63 (48 = ones for l, rest zero)
    for (int i = tid; i < 16 * 72; i += 128) {
        const int r = 48 + i / 72, c = i - (i / 72) * 72;
        Vts[r][c] = (r == 48) ? (_Float16)1.0f : (_Float16)0.0f;
    }

    // Q B-frags: query = qt*64 + wq*32 + ln, dh = 16i + 8h + 0..7
    f16x8 qf[3];
    {
        const _Float16* qp = qh + (size_t)(bh * 2048 + qt * 64 + wq * 32 + ln) * 48 + 8 * h;
        qf[0] = *(const f16x8*)qp;
        qf[1] = *(const f16x8*)(qp + 16);
        qf[2] = *(const f16x8*)(qp + 32);
    }

    f32x16 o0, o1;
    #pragma unroll
    for (int r = 0; r < 16; r++) { o0[r] = 0.f; o1[r] = 0.f; }

    const _Float16* kbase = kh + (size_t)bh * 2048 * 48;
    const _Float16* vbase = vt + (size_t)bh * 48 * 2048;

    // staging: K 384 chunks (row=c/6, col=(c%6)*8); V 384 (row=c>>3, col=(c&7)*8)
    int krow[3], kcol[3], vrow[3];
    const _Float16 *ksp[3], *vsp[3];
    const int vcol = (tid & 7) * 8;    // (tid+128j)&7 == tid&7
    #pragma unroll
    for (int j = 0; j < 3; j++) {
        const int c = tid + 128 * j;
        krow[j] = c / 6;  kcol[j] = (c % 6) * 8;
        vrow[j] = c >> 3;
        ksp[j] = kbase + (size_t)krow[j] * 48 + kcol[j];
        vsp[j] = vbase + (size_t)vrow[j] * 2048 + vcol;
    }
    f16x8 rk[3], rv[3];
    #pragma unroll
    for (int j = 0; j < 3; j++) { rk[j] = *(const f16x8*)ksp[j]; rv[j] = *(const f16x8*)vsp[j]; }

    for (int kt = 0; kt < 2048; kt += 64) {
        __syncthreads();
        #pragma unroll
        for (int j = 0; j < 3; j++) {
            *(f16x8*)&Ks[krow[j]][kcol[j]] = rk[j];
            *(f16x8*)&Vts[vrow[j]][vcol]   = rv[j];
        }
        __syncthreads();
        if (kt + 64 < 2048) {
            #pragma unroll
            for (int j = 0; j < 3; j++) {
                rk[j] = *(const f16x8*)(ksp[j] + (size_t)(kt + 64) * 48);
                rv[j] = *(const f16x8*)(vsp[j] + kt + 64);
            }
        }

        // ---- S^T = K.Q^T per key-group; P = exp2(S^T) -> Ps ----
        #pragma unroll
        for (int kg = 0; kg < 2; kg++) {
            f32x16 s;
            #pragma unroll
            for (int r = 0; r < 16; r++) s[r] = 0.f;
            #pragma unroll
            for (int i = 0; i < 3; i++) {
                const f16x8 ka = *(const f16x8*)&Ks[kg * 32 + ln][16 * i + 8 * h];
                s = __builtin_amdgcn_mfma_f32_32x32x16_f16(ka, qf[i], s, 0, 0, 0);
            }
            #pragma unroll
            for (int q = 0; q < 4; q++) {
                f16x4 pk;
                pk[0] = (_Float16)exp2f(s[4 * q + 0]);
                pk[1] = (_Float16)exp2f(s[4 * q + 1]);
                pk[2] = (_Float16)exp2f(s[4 * q + 2]);
                pk[3] = (_Float16)exp2f(s[4 * q + 3]);
                *(f16x4*)&Ps[wq * 32 + ln][kg * 32 + 8 * q + 4 * h] = pk;
            }
        }

        // ---- O += P.V : 4 K=16 chunks x 2 col-groups ----
        #pragma unroll
        for (int c = 0; c < 4; c++) {
            const f16x8 pa = *(const f16x8*)&Ps[wq * 32 + ln][16 * c + 8 * h];
            const f16x8 bv0 = *(const f16x8*)&Vts[ln][16 * c + 8 * h];
            o0 = __builtin_amdgcn_mfma_f32_32x32x16_f16(pa, bv0, o0, 0, 0, 0);
            const f16x8 bv1 = *(const f16x8*)&Vts[32 + ln][16 * c + 8 * h];
            o1 = __builtin_amdgcn_mfma_f32_32x32x16_f16(pa, bv1, o1, 0, 0, 0);
        }
    }

    // ---- normalize + store. l = O col 48 = cg1 col 16 -> lane h*32+16 ----
    const int b = bh >> 3, hd = bh & 7;
    #pragma unroll
    for (int r = 0; r < 16; r++) {
        const float lr = __shfl(o1[r], (lane & 32) + 16);
        const float inv = 1.f / lr;
        const int q = qt * 64 + wq * 32 + (r & 3) + 8 * (r >> 2) + 4 * h;
        _Float16* orow = ab + (size_t)(b * 2048 + q) * 384 + hd * 48;
        orow[ln] = (_Float16)(o0[r] * inv);
        if (ln < 16) orow[32 + ln] = (_Float16)(o1[r] * inv);
    }
}

// ---------------------------------------------------------------------------
// Proj GEMM: A = ab[8192][384] f16, Bt = wprojt[384][384] f16, +bias -> fp32
// 64x64 tile, BK=64, padded LDS, reg-prefetch.
// ---------------------------------------------------------------------------
__global__ __launch_bounds__(256) void proj_f16(const _Float16* __restrict__ A,
                                                const _Float16* __restrict__ Bt,
                                                const float* __restrict__ bias,
                                                float* __restrict__ out)
{
    __shared__ _Float16 As[64][72];
    __shared__ _Float16 Bs[64][72];
    const int tid = threadIdx.x;
    const int w = tid >> 6, lane = tid & 63, cl = lane & 15, quad = lane >> 4;
    const int bm = blockIdx.x, bn = blockIdx.y;

    f32x4 acc[4];
    const f32x4 z4 = {0.f, 0.f, 0.f, 0.f};
    #pragma unroll
    for (int t = 0; t < 4; t++) acc[t] = z4;

    const int ar = tid >> 3, ac = (tid & 7) * 8;
    const _Float16* Ag = A  + (size_t)(bm * 64 + ar) * 384 + ac;
    const _Float16* Bg = Bt + (size_t)(bn * 64 + ar) * 384 + ac;

    f16x8 pa[2], pb[2];
    #pragma unroll
    for (int j = 0; j < 2; j++) {
        pa[j] = *(const f16x8*)(Ag + (size_t)(32 * j) * 384);
        pb[j] = *(const f16x8*)(Bg + (size_t)(32 * j) * 384);
    }

    for (int k0 = 0; k0 < 384; k0 += 64) {
        __syncthreads();
        #pragma unroll
        for (int j = 0; j < 2; j++) {
            *(f16x8*)&As[ar + 32 * j][ac] = pa[j];
            *(f16x8*)&Bs[ar + 32 * j][ac] = pb[j];
        }
        __syncthreads();
        if (k0 + 64 < 384) {
            #pragma unroll
            for (int j = 0; j < 2; j++) {
                pa[j] = *(const f16x8*)(Ag + (size_t)(32 * j) * 384 + k0 + 64);
                pb[j] = *(const f16x8*)(Bg + (size_t)(32 * j) * 384 + k0 + 64);
            }
        }
        #pragma unroll
        for (int kh2 = 0; kh2 < 2; kh2++) {
            const f16x8 af = *(const f16x8*)&As[w * 16 + cl][kh2 * 32 + quad * 8];
            #pragma unroll
            for (int t = 0; t < 4; t++) {
                const f16x8 bf = *(const f16x8*)&Bs[t * 16 + cl][kh2 * 32 + quad * 8];
                acc[t] = __builtin_amdgcn_mfma_f32_16x16x32_f16(af, bf, acc[t], 0, 0, 0);
            }
        }
    }

    #pragma unroll
    for (int t = 0; t < 4; t++) {
        const int col = bn * 64 + t * 16 + cl;
        const float bv = bias[col];
        #pragma unroll
        for (int r = 0; r < 4; r++) {
            const int row = bm * 64 + w * 16 + quad * 4 + r;
            out[(size_t)row * 384 + col] = acc[t][r] + bv;
        }
    }
}

// ---------------------------------------------------------------------------
extern "C" void kernel_launch(void* const* d_in, const int* in_sizes, int n_in,
                              void* d_out, int out_size, void* d_ws, size_t ws_size,
                              hipStream_t stream) {
    const float* x     = (const float*)d_in[0];  // [4,2048,384]
    const float* Wqkv  = (const float*)d_in[1];  // [384,1152]
    const float* Wproj = (const float*)d_in[2];  // [384,384]
    const float* bproj = (const float*)d_in[3];  // [384]
    float* out = (float*)d_out;

    char* ws = (char*)d_ws;
    _Float16* wqkvt  = (_Float16*)(ws + 0);          // 1152*384*2 =   884,736
    _Float16* wprojt = (_Float16*)(ws + 884736);     // 384*384*2  =   294,912
    _Float16* qh     = (_Float16*)(ws + 1179648);    // 32*2048*48*2 = 6,291,456
    _Float16* kh     = (_Float16*)(ws + 7471104);    // 6,291,456
    _Float16* vt     = (_Float16*)(ws + 13762560);   // 6,291,456
    _Float16* ab     = (_Float16*)(ws + 20054016);   // 6,291,456
    // total 26,345,472 B

    prep<<<144, 256, 0, stream>>>(Wqkv, Wproj, wqkvt, wprojt);
    qkv_f16<<<dim3(64, 18), 256, 0, stream>>>(x, wqkvt, qh, kh, vt);
    attn_f16<<<dim3(32, 32), 128, 0, stream>>>(qh, kh, vt, ab);
    proj_f16<<<dim3(128, 6), 256, 0, stream>>>(ab, wprojt, bproj, out);
}

// Round 13
// 152.561 us; speedup vs baseline: 1.2594x; 1.0650x over previous
//
#include <hip/hip_runtime.h>
#include <hip/hip_bf16.h>

// Attention B=4,N=2048,D=384,H=8,DH=48 — Round 12:
//  - attn: R9 verbatim (TQ=128, 256 thr, 4 full-key waves — best measured 65.6us)
//  - qkv: q/k epilogue ALSO via LDS transpose -> f16x8 coalesced stores
//    (was 32 scattered b16 stores/thread); V path unchanged from R9.

typedef _Float16 f16x8 __attribute__((ext_vector_type(8)));
typedef _Float16 f16x4 __attribute__((ext_vector_type(4)));
typedef float    f32x4 __attribute__((ext_vector_type(4)));
typedef float    f32x16 __attribute__((ext_vector_type(16)));

// scale * log2(e) = 48^-0.5 * 1.4426950408889634
#define QSCL 0.20822035963448658f

// ---------------------------------------------------------------------------
// prep: LDS-tiled coalesced weight transposes (Wqkv^T, Wproj^T) -> f16 [n][k]
// ---------------------------------------------------------------------------
__global__ __launch_bounds__(256) void prep(const float* __restrict__ wq,
                                            const float* __restrict__ wp,
                                            _Float16* __restrict__ wqt,
                                            _Float16* __restrict__ wpt)
{
    __shared__ _Float16 t[64][65];
    const int blk = blockIdx.x, tid = threadIdx.x;
    const float* src; _Float16* dst; int Nn, k0, n0;
    if (blk < 108) {            // Wqkv: 6 k-tiles x 18 n-tiles
        src = wq; dst = wqt; Nn = 1152;
        k0 = (blk % 6) * 64; n0 = (blk / 6) * 64;
    } else {                    // Wproj: 6 x 6
        const int b2 = blk - 108;
        src = wp; dst = wpt; Nn = 384;
        k0 = (b2 % 6) * 64; n0 = (b2 / 6) * 64;
    }
    #pragma unroll
    for (int i = 0; i < 16; i++) {
        const int id = tid + i * 256;            // 0..4095
        const int k = id >> 6, n = id & 63;      // coalesced over n
        t[k][n] = (_Float16)src[(size_t)(k0 + k) * Nn + n0 + n];
    }
    __syncthreads();
    #pragma unroll
    for (int i = 0; i < 16; i++) {
        const int id = tid + i * 256;
        const int n = id >> 6, k = id & 63;      // coalesced over k
        dst[(size_t)(n0 + n) * 384 + k0 + k] = t[k][n];
    }
}

// ---------------------------------------------------------------------------
// QKV GEMM: A = x[8192][384] fp32 (cvt at staging), Bt = wqkvt[1152][384] f16.
// 128x64 tile, BK=64, padded LDS, 16x16x32 MFMA, 4 waves, reg-prefetch.
// Epilogue: ALL outputs via LDS transpose -> coalesced f16x8 stores.
// ---------------------------------------------------------------------------
union QkvSmem {
    struct { _Float16 As[128][72]; _Float16 Bs[64][72]; } g;  // 27648 B
    _Float16 Ts[64][136];    // V transpose   [col][n]   17408 B
    _Float16 Ts2[128][72];   // q/k transpose [row][col] 18432 B
};

__global__ __launch_bounds__(256) void qkv_f16(const float* __restrict__ X,
                                               const _Float16* __restrict__ Bt,
                                               _Float16* __restrict__ qh,
                                               _Float16* __restrict__ kh,
                                               _Float16* __restrict__ vt)
{
    __shared__ QkvSmem sm;
    const int tid = threadIdx.x;
    const int w = tid >> 6, lane = tid & 63, cl = lane & 15, quad = lane >> 4;
    const int bm = blockIdx.x, bn = blockIdx.y;

    f32x4 acc[2][4];
    const f32x4 z4 = {0.f, 0.f, 0.f, 0.f};
    #pragma unroll
    for (int mi = 0; mi < 2; mi++)
        #pragma unroll
        for (int t = 0; t < 4; t++) acc[mi][t] = z4;

    const int ar = tid >> 3, ac = (tid & 7) * 8;
    const float*    Ag = X  + (size_t)(bm * 128 + ar) * 384 + ac;
    const _Float16* Bg = Bt + (size_t)(bn * 64  + ar) * 384 + ac;

    float4 pa0[4], pa1[4];
    f16x8 pb[2];
    #pragma unroll
    for (int j = 0; j < 4; j++) {
        pa0[j] = *(const float4*)(Ag + (size_t)(32 * j) * 384);
        pa1[j] = *(const float4*)(Ag + (size_t)(32 * j) * 384 + 4);
    }
    #pragma unroll
    for (int j = 0; j < 2; j++) pb[j] = *(const f16x8*)(Bg + (size_t)(32 * j) * 384);

    for (int k0 = 0; k0 < 384; k0 += 64) {
        __syncthreads();
        #pragma unroll
        for (int j = 0; j < 4; j++) {
            f16x8 hh;
            hh[0] = (_Float16)pa0[j].x; hh[1] = (_Float16)pa0[j].y;
            hh[2] = (_Float16)pa0[j].z; hh[3] = (_Float16)pa0[j].w;
            hh[4] = (_Float16)pa1[j].x; hh[5] = (_Float16)pa1[j].y;
            hh[6] = (_Float16)pa1[j].z; hh[7] = (_Float16)pa1[j].w;
            *(f16x8*)&sm.g.As[ar + 32 * j][ac] = hh;
        }
        #pragma unroll
        for (int j = 0; j < 2; j++) *(f16x8*)&sm.g.Bs[ar + 32 * j][ac] = pb[j];
        __syncthreads();
        if (k0 + 64 < 384) {
            #pragma unroll
            for (int j = 0; j < 4; j++) {
                pa0[j] = *(const float4*)(Ag + (size_t)(32 * j) * 384 + k0 + 64);
                pa1[j] = *(const float4*)(Ag + (size_t)(32 * j) * 384 + k0 + 68);
            }
            #pragma unroll
            for (int j = 0; j < 2; j++)
                pb[j] = *(const f16x8*)(Bg + (size_t)(32 * j) * 384 + k0 + 64);
        }
        #pragma unroll
        for (int kh2 = 0; kh2 < 2; kh2++) {
            f16x8 bf[4];
            #pragma unroll
            for (int t = 0; t < 4; t++)
                bf[t] = *(const f16x8*)&sm.g.Bs[t * 16 + cl][kh2 * 32 + quad * 8];
            #pragma unroll
            for (int mi = 0; mi < 2; mi++) {
                const f16x8 af = *(const f16x8*)&sm.g.As[w * 32 + mi * 16 + cl][kh2 * 32 + quad * 8];
                #pragma unroll
                for (int t = 0; t < 4; t++)
                    acc[mi][t] = __builtin_amdgcn_mfma_f32_16x16x32_f16(af, bf[t], acc[mi][t], 0, 0, 0);
            }
        }
    }

    const int s = (bn * 64) / 384;    // uniform per block
    if (s == 2) {
        // ---- V: LDS transpose [col][n] -> coalesced stores along n ----
        __syncthreads();              // all fragment reads done
        #pragma unroll
        for (int t = 0; t < 4; t++)
            #pragma unroll
            for (int mi = 0; mi < 2; mi++)
                #pragma unroll
                for (int r = 0; r < 4; r++)
                    sm.Ts[t * 16 + cl][w * 32 + mi * 16 + quad * 4 + r] =
                        (_Float16)acc[mi][t][r];
        __syncthreads();
        const int colbase = bn * 64 - 768;       // 0..320
        const int b  = (bm * 128) >> 11;         // constant per block
        const int n0 = (bm * 128) & 2047;
        #pragma unroll
        for (int i = 0; i < 4; i++) {
            const int c = i * 256 + tid;         // 0..1023 chunks of 8
            const int col = c >> 4, nc = c & 15;
            const int gcol = colbase + col;
            const int head = gcol / 48, d = gcol - head * 48;
            const int bh = b * 8 + head;
            *(f16x8*)&vt[(size_t)(bh * 48 + d) * 2048 + n0 + nc * 8] =
                *(const f16x8*)&sm.Ts[col][nc * 8];
        }
    } else {
        // ---- q/k: LDS transpose [row][col] -> coalesced f16x8 stores ----
        __syncthreads();              // all fragment reads done
        const float scl = (s == 0) ? QSCL : 1.0f;
        #pragma unroll
        for (int t = 0; t < 4; t++)
            #pragma unroll
            for (int mi = 0; mi < 2; mi++)
                #pragma unroll
                for (int r = 0; r < 4; r++)
                    sm.Ts2[w * 32 + mi * 16 + quad * 4 + r][t * 16 + cl] =
                        (_Float16)(acc[mi][t][r] * scl);
        __syncthreads();
        _Float16* dst = (s == 0) ? qh : kh;
        const int colbase = bn * 64 - s * 384;   // 0..320
        const int b  = (bm * 128) >> 11;
        const int n0 = (bm * 128) & 2047;
        #pragma unroll
        for (int i = 0; i < 4; i++) {
            const int c = i * 256 + tid;         // 0..1023 chunks of 8
            const int row = c >> 3, ch = c & 7;
            const int gcol = colbase + ch * 8;   // multiple of 8; 48=6x8 -> no straddle
            const int head = gcol / 48, d = gcol - head * 48;
            const int bh = b * 8 + head;
            *(f16x8*)&dst[(size_t)(bh * 2048 + n0 + row) * 48 + d] =
                *(const f16x8*)&sm.Ts2[row][ch * 8];
        }
    }
}

// ---------------------------------------------------------------------------
// Flash attention, 32x32x16 f16 MFMA, no-max softmax, reg-prefetch staging.
// Block 256 = 4 waves; 128 queries of one (b,h); 64-key tiles. (R9/R6 version)
// ---------------------------------------------------------------------------
__global__ __launch_bounds__(256) void attn_f16(const _Float16* __restrict__ qh,
                                                const _Float16* __restrict__ kh,
                                                const _Float16* __restrict__ vt,
                                                _Float16* __restrict__ ab)
{
    __shared__ _Float16 Ks[64][56];    // [key][dh]    7 KB
    __shared__ _Float16 Vts[64][72];   // [dh][key]    9 KB; row 48 ones, 49-63 zero
    __shared__ _Float16 Ps[128][72];   // [query][key] 18 KB
    const int tid = threadIdx.x;
    const int w = tid >> 6, lane = tid & 63, ln = lane & 31, h = lane >> 5;
    const int bh = blockIdx.x, qt = blockIdx.y;

    // one-time: Vts rows 48..63 (48 = ones for l, rest zero)
    for (int i = tid; i < 16 * 72; i += 256) {
        const int r = 48 + i / 72, c = i - (i / 72) * 72;
        Vts[r][c] = (r == 48) ? (_Float16)1.0f : (_Float16)0.0f;
    }

    // Q B-frags (3, dh = 16i + 8h + 0..7), query = qt*128 + w*32 + ln
    f16x8 qf[3];
    {
        const _Float16* qp = qh + (size_t)(bh * 2048 + qt * 128 + w * 32 + ln) * 48 + 8 * h;
        qf[0] = *(const f16x8*)qp;
        qf[1] = *(const f16x8*)(qp + 16);
        qf[2] = *(const f16x8*)(qp + 32);
    }

    f32x16 o0, o1;
    #pragma unroll
    for (int r = 0; r < 16; r++) { o0[r] = 0.f; o1[r] = 0.f; }

    const _Float16* kbase = kh + (size_t)bh * 2048 * 48;
    const _Float16* vbase = vt + (size_t)bh * 48 * 2048;

    const int kr0 = tid / 6,         kc0 = (tid % 6) * 8;
    const int kid1 = tid + 256;
    const int kr1 = kid1 / 6,        kc1 = (kid1 % 6) * 8;
    const int vr0 = tid >> 3,        vc0 = (tid & 7) * 8;
    const int vr1 = (tid + 256) >> 3;
    const _Float16* ks0 = kbase + (size_t)kr0 * 48 + kc0;
    const _Float16* ks1 = kbase + (size_t)kr1 * 48 + kc1;
    const _Float16* vs0 = vbase + (size_t)vr0 * 2048 + vc0;
    const _Float16* vs1 = vbase + (size_t)vr1 * 2048 + vc0;

    // prefetch tile 0 into registers
    f16x8 rk0 = *(const f16x8*)ks0;
    f16x8 rv0 = *(const f16x8*)vs0;
    f16x8 rk1, rv1;
    if (tid < 128) { rk1 = *(const f16x8*)ks1; rv1 = *(const f16x8*)vs1; }

    for (int kt = 0; kt < 2048; kt += 64) {
        __syncthreads();
        *(f16x8*)&Ks[kr0][kc0]  = rk0;
        *(f16x8*)&Vts[vr0][vc0] = rv0;
        if (tid < 128) {
            *(f16x8*)&Ks[kr1][kc1]  = rk1;
            *(f16x8*)&Vts[vr1][vc0] = rv1;
        }
        __syncthreads();
        if (kt + 64 < 2048) {        // issue next-tile loads; waited at next write
            rk0 = *(const f16x8*)(ks0 + (size_t)(kt + 64) * 48);
            rv0 = *(const f16x8*)(vs0 + kt + 64);
            if (tid < 128) {
                rk1 = *(const f16x8*)(ks1 + (size_t)(kt + 64) * 48);
                rv1 = *(const f16x8*)(vs1 + kt + 64);
            }
        }

        // ---- S^T = K.Q^T : per key-group, C[key 32][query 32] ----
        f32x16 s0, s1;
        #pragma unroll
        for (int r = 0; r < 16; r++) { s0[r] = 0.f; s1[r] = 0.f; }
        #pragma unroll
        for (int i = 0; i < 3; i++) {
            const f16x8 ka0 = *(const f16x8*)&Ks[ln][16 * i + 8 * h];
            s0 = __builtin_amdgcn_mfma_f32_32x32x16_f16(ka0, qf[i], s0, 0, 0, 0);
            const f16x8 ka1 = *(const f16x8*)&Ks[32 + ln][16 * i + 8 * h];
            s1 = __builtin_amdgcn_mfma_f32_32x32x16_f16(ka1, qf[i], s1, 0, 0, 0);
        }

        // ---- P = exp2(S^T) -> Ps[query][key], b64 packed stores ----
        #pragma unroll
        for (int q = 0; q < 4; q++) {
            f16x4 pk;
            pk[0] = (_Float16)exp2f(s0[4 * q + 0]);
            pk[1] = (_Float16)exp2f(s0[4 * q + 1]);
            pk[2] = (_Float16)exp2f(s0[4 * q + 2]);
            pk[3] = (_Float16)exp2f(s0[4 * q + 3]);
            *(f16x4*)&Ps[w * 32 + ln][8 * q + 4 * h] = pk;
            f16x4 pk1;
            pk1[0] = (_Float16)exp2f(s1[4 * q + 0]);
            pk1[1] = (_Float16)exp2f(s1[4 * q + 1]);
            pk1[2] = (_Float16)exp2f(s1[4 * q + 2]);
            pk1[3] = (_Float16)exp2f(s1[4 * q + 3]);
            *(f16x4*)&Ps[w * 32 + ln][32 + 8 * q + 4 * h] = pk1;
        }

        // ---- O += P.V : A=Ps rows (wave-private), B=Vts ----
        #pragma unroll
        for (int i = 0; i < 4; i++) {
            const f16x8 pa = *(const f16x8*)&Ps[w * 32 + ln][16 * i + 8 * h];
            const f16x8 v0 = *(const f16x8*)&Vts[ln][16 * i + 8 * h];
            o0 = __builtin_amdgcn_mfma_f32_32x32x16_f16(pa, v0, o0, 0, 0, 0);
            const f16x8 v1 = *(const f16x8*)&Vts[32 + ln][16 * i + 8 * h];
            o1 = __builtin_amdgcn_mfma_f32_32x32x16_f16(pa, v1, o1, 0, 0, 0);
        }
    }

    // ---- normalize + store. l = O col 48 = cg1 col 16 -> lane h*32+16 ----
    const int b = bh >> 3, hd = bh & 7;
    #pragma unroll
    for (int r = 0; r < 16; r++) {
        const float lr = __shfl(o1[r], (lane & 32) + 16);
        const float inv = 1.f / lr;
        const int q = qt * 128 + w * 32 + (r & 3) + 8 * (r >> 2) + 4 * h;
        _Float16* orow = ab + (size_t)(b * 2048 + q) * 384 + hd * 48;
        orow[ln] = (_Float16)(o0[r] * inv);
        if (ln < 16) orow[32 + ln] = (_Float16)(o1[r] * inv);
    }
}

// ---------------------------------------------------------------------------
// Proj GEMM: A = ab[8192][384] f16, Bt = wprojt[384][384] f16, +bias -> fp32
// 64x64 tile, BK=64, padded LDS, reg-prefetch.
// ---------------------------------------------------------------------------
__global__ __launch_bounds__(256) void proj_f16(const _Float16* __restrict__ A,
                                                const _Float16* __restrict__ Bt,
                                                const float* __restrict__ bias,
                                                float* __restrict__ out)
{
    __shared__ _Float16 As[64][72];
    __shared__ _Float16 Bs[64][72];
    const int tid = threadIdx.x;
    const int w = tid >> 6, lane = tid & 63, cl = lane & 15, quad = lane >> 4;
    const int bm = blockIdx.x, bn = blockIdx.y;

    f32x4 acc[4];
    const f32x4 z4 = {0.f, 0.f, 0.f, 0.f};
    #pragma unroll
    for (int t = 0; t < 4; t++) acc[t] = z4;

    const int ar = tid >> 3, ac = (tid & 7) * 8;
    const _Float16* Ag = A  + (size_t)(bm * 64 + ar) * 384 + ac;
    const _Float16* Bg = Bt + (size_t)(bn * 64 + ar) * 384 + ac;

    f16x8 pa[2], pb[2];
    #pragma unroll
    for (int j = 0; j < 2; j++) {
        pa[j] = *(const f16x8*)(Ag + (size_t)(32 * j) * 384);
        pb[j] = *(const f16x8*)(Bg + (size_t)(32 * j) * 384);
    }

    for (int k0 = 0; k0 < 384; k0 += 64) {
        __syncthreads();
        #pragma unroll
        for (int j = 0; j < 2; j++) {
            *(f16x8*)&As[ar + 32 * j][ac] = pa[j];
            *(f16x8*)&Bs[ar + 32 * j][ac] = pb[j];
        }
        __syncthreads();
        if (k0 + 64 < 384) {
            #pragma unroll
            for (int j = 0; j < 2; j++) {
                pa[j] = *(const f16x8*)(Ag + (size_t)(32 * j) * 384 + k0 + 64);
                pb[j] = *(const f16x8*)(Bg + (size_t)(32 * j) * 384 + k0 + 64);
            }
        }
        #pragma unroll
        for (int kh2 = 0; kh2 < 2; kh2++) {
            const f16x8 af = *(const f16x8*)&As[w * 16 + cl][kh2 * 32 + quad * 8];
            #pragma unroll
            for (int t = 0; t < 4; t++) {
                const f16x8 bf = *(const f16x8*)&Bs[t * 16 + cl][kh2 * 32 + quad * 8];
                acc[t] = __builtin_amdgcn_mfma_f32_16x16x32_f16(af, bf, acc[t], 0, 0, 0);
            }
        }
    }

    #pragma unroll
    for (int t = 0; t < 4; t++) {
        const int col = bn * 64 + t * 16 + cl;
        const float bv = bias[col];
        #pragma unroll
        for (int r = 0; r < 4; r++) {
            const int row = bm * 64 + w * 16 + quad * 4 + r;
            out[(size_t)row * 384 + col] = acc[t][r] + bv;
        }
    }
}

// ---------------------------------------------------------------------------
extern "C" void kernel_launch(void* const* d_in, const int* in_sizes, int n_in,
                              void* d_out, int out_size, void* d_ws, size_t ws_size,
                              hipStream_t stream) {
    const float* x     = (const float*)d_in[0];  // [4,2048,384]
    const float* Wqkv  = (const float*)d_in[1];  // [384,1152]
    const float* Wproj = (const float*)d_in[2];  // [384,384]
    const float* bproj = (const float*)d_in[3];  // [384]
    float* out = (float*)d_out;

    char* ws = (char*)d_ws;
    _Float16* wqkvt  = (_Float16*)(ws + 0);          // 1152*384*2 =   884,736
    _Float16* wprojt = (_Float16*)(ws + 884736);     // 384*384*2  =   294,912
    _Float16* qh     = (_Float16*)(ws + 1179648);    // 32*2048*48*2 = 6,291,456
    _Float16* kh     = (_Float16*)(ws + 7471104);    // 6,291,456
    _Float16* vt     = (_Float16*)(ws + 13762560);   // 6,291,456
    _Float16* ab     = (_Float16*)(ws + 20054016);   // 6,291,456
    // total 26,345,472 B

    prep<<<144, 256, 0, stream>>>(Wqkv, Wproj, wqkvt, wprojt);
    qkv_f16<<<dim3(64, 18), 256, 0, stream>>>(x, wqkvt, qh, kh, vt);
    attn_f16<<<dim3(32, 16), 256, 0, stream>>>(qh, kh, vt, ab);
    proj_f16<<<dim3(128, 6), 256, 0, stream>>>(ab, wprojt, bproj, out);
}

// Round 14
// 149.490 us; speedup vs baseline: 1.2853x; 1.0205x over previous
//
#include <hip/hip_runtime.h>
#include <hip/hip_bf16.h>

// Attention B=4,N=2048,D=384,H=8,DH=48 — Round 13:
//  - attn: P round-trip ELIMINATED. PV computed as O^T = V^T . P^T where the
//    S^T MFMA's C-layout is directly a valid B-operand under the key
//    permutation kappa(c,h,j)=16c+4h+(j&3)+8(j>>2); V^T staged pre-permuted.
//    LDS ops/wave/tile 29 -> ~19; LDS 35KB -> ~17KB. Epilogue via LDS transpose.
//  - prep / qkv / proj unchanged from R12.

typedef _Float16 f16x8 __attribute__((ext_vector_type(8)));
typedef _Float16 f16x4 __attribute__((ext_vector_type(4)));
typedef float    f32x4 __attribute__((ext_vector_type(4)));
typedef float    f32x16 __attribute__((ext_vector_type(16)));

// scale * log2(e) = 48^-0.5 * 1.4426950408889634
#define QSCL 0.20822035963448658f

// ---------------------------------------------------------------------------
// prep: LDS-tiled coalesced weight transposes (Wqkv^T, Wproj^T) -> f16 [n][k]
// ---------------------------------------------------------------------------
__global__ __launch_bounds__(256) void prep(const float* __restrict__ wq,
                                            const float* __restrict__ wp,
                                            _Float16* __restrict__ wqt,
                                            _Float16* __restrict__ wpt)
{
    __shared__ _Float16 t[64][65];
    const int blk = blockIdx.x, tid = threadIdx.x;
    const float* src; _Float16* dst; int Nn, k0, n0;
    if (blk < 108) {            // Wqkv: 6 k-tiles x 18 n-tiles
        src = wq; dst = wqt; Nn = 1152;
        k0 = (blk % 6) * 64; n0 = (blk / 6) * 64;
    } else {                    // Wproj: 6 x 6
        const int b2 = blk - 108;
        src = wp; dst = wpt; Nn = 384;
        k0 = (b2 % 6) * 64; n0 = (b2 / 6) * 64;
    }
    #pragma unroll
    for (int i = 0; i < 16; i++) {
        const int id = tid + i * 256;            // 0..4095
        const int k = id >> 6, n = id & 63;      // coalesced over n
        t[k][n] = (_Float16)src[(size_t)(k0 + k) * Nn + n0 + n];
    }
    __syncthreads();
    #pragma unroll
    for (int i = 0; i < 16; i++) {
        const int id = tid + i * 256;
        const int n = id >> 6, k = id & 63;      // coalesced over k
        dst[(size_t)(n0 + n) * 384 + k0 + k] = t[k][n];
    }
}

// ---------------------------------------------------------------------------
// QKV GEMM: A = x[8192][384] fp32 (cvt at staging), Bt = wqkvt[1152][384] f16.
// 128x64 tile, BK=64, padded LDS, 16x16x32 MFMA, 4 waves, reg-prefetch.
// Epilogue: ALL outputs via LDS transpose -> coalesced f16x8 stores.
// ---------------------------------------------------------------------------
union QkvSmem {
    struct { _Float16 As[128][72]; _Float16 Bs[64][72]; } g;  // 27648 B
    _Float16 Ts[64][136];    // V transpose   [col][n]   17408 B
    _Float16 Ts2[128][72];   // q/k transpose [row][col] 18432 B
};

__global__ __launch_bounds__(256) void qkv_f16(const float* __restrict__ X,
                                               const _Float16* __restrict__ Bt,
                                               _Float16* __restrict__ qh,
                                               _Float16* __restrict__ kh,
                                               _Float16* __restrict__ vt)
{
    __shared__ QkvSmem sm;
    const int tid = threadIdx.x;
    const int w = tid >> 6, lane = tid & 63, cl = lane & 15, quad = lane >> 4;
    const int bm = blockIdx.x, bn = blockIdx.y;

    f32x4 acc[2][4];
    const f32x4 z4 = {0.f, 0.f, 0.f, 0.f};
    #pragma unroll
    for (int mi = 0; mi < 2; mi++)
        #pragma unroll
        for (int t = 0; t < 4; t++) acc[mi][t] = z4;

    const int ar = tid >> 3, ac = (tid & 7) * 8;
    const float*    Ag = X  + (size_t)(bm * 128 + ar) * 384 + ac;
    const _Float16* Bg = Bt + (size_t)(bn * 64  + ar) * 384 + ac;

    float4 pa0[4], pa1[4];
    f16x8 pb[2];
    #pragma unroll
    for (int j = 0; j < 4; j++) {
        pa0[j] = *(const float4*)(Ag + (size_t)(32 * j) * 384);
        pa1[j] = *(const float4*)(Ag + (size_t)(32 * j) * 384 + 4);
    }
    #pragma unroll
    for (int j = 0; j < 2; j++) pb[j] = *(const f16x8*)(Bg + (size_t)(32 * j) * 384);

    for (int k0 = 0; k0 < 384; k0 += 64) {
        __syncthreads();
        #pragma unroll
        for (int j = 0; j < 4; j++) {
            f16x8 hh;
            hh[0] = (_Float16)pa0[j].x; hh[1] = (_Float16)pa0[j].y;
            hh[2] = (_Float16)pa0[j].z; hh[3] = (_Float16)pa0[j].w;
            hh[4] = (_Float16)pa1[j].x; hh[5] = (_Float16)pa1[j].y;
            hh[6] = (_Float16)pa1[j].z; hh[7] = (_Float16)pa1[j].w;
            *(f16x8*)&sm.g.As[ar + 32 * j][ac] = hh;
        }
        #pragma unroll
        for (int j = 0; j < 2; j++) *(f16x8*)&sm.g.Bs[ar + 32 * j][ac] = pb[j];
        __syncthreads();
        if (k0 + 64 < 384) {
            #pragma unroll
            for (int j = 0; j < 4; j++) {
                pa0[j] = *(const float4*)(Ag + (size_t)(32 * j) * 384 + k0 + 64);
                pa1[j] = *(const float4*)(Ag + (size_t)(32 * j) * 384 + k0 + 68);
            }
            #pragma unroll
            for (int j = 0; j < 2; j++)
                pb[j] = *(const f16x8*)(Bg + (size_t)(32 * j) * 384 + k0 + 64);
        }
        #pragma unroll
        for (int kh2 = 0; kh2 < 2; kh2++) {
            f16x8 bf[4];
            #pragma unroll
            for (int t = 0; t < 4; t++)
                bf[t] = *(const f16x8*)&sm.g.Bs[t * 16 + cl][kh2 * 32 + quad * 8];
            #pragma unroll
            for (int mi = 0; mi < 2; mi++) {
                const f16x8 af = *(const f16x8*)&sm.g.As[w * 32 + mi * 16 + cl][kh2 * 32 + quad * 8];
                #pragma unroll
                for (int t = 0; t < 4; t++)
                    acc[mi][t] = __builtin_amdgcn_mfma_f32_16x16x32_f16(af, bf[t], acc[mi][t], 0, 0, 0);
            }
        }
    }

    const int s = (bn * 64) / 384;    // uniform per block
    if (s == 2) {
        // ---- V: LDS transpose [col][n] -> coalesced stores along n ----
        __syncthreads();              // all fragment reads done
        #pragma unroll
        for (int t = 0; t < 4; t++)
            #pragma unroll
            for (int mi = 0; mi < 2; mi++)
                #pragma unroll
                for (int r = 0; r < 4; r++)
                    sm.Ts[t * 16 + cl][w * 32 + mi * 16 + quad * 4 + r] =
                        (_Float16)acc[mi][t][r];
        __syncthreads();
        const int colbase = bn * 64 - 768;       // 0..320
        const int b  = (bm * 128) >> 11;         // constant per block
        const int n0 = (bm * 128) & 2047;
        #pragma unroll
        for (int i = 0; i < 4; i++) {
            const int c = i * 256 + tid;         // 0..1023 chunks of 8
            const int col = c >> 4, nc = c & 15;
            const int gcol = colbase + col;
            const int head = gcol / 48, d = gcol - head * 48;
            const int bh = b * 8 + head;
            *(f16x8*)&vt[(size_t)(bh * 48 + d) * 2048 + n0 + nc * 8] =
                *(const f16x8*)&sm.Ts[col][nc * 8];
        }
    } else {
        // ---- q/k: LDS transpose [row][col] -> coalesced f16x8 stores ----
        __syncthreads();              // all fragment reads done
        const float scl = (s == 0) ? QSCL : 1.0f;
        #pragma unroll
        for (int t = 0; t < 4; t++)
            #pragma unroll
            for (int mi = 0; mi < 2; mi++)
                #pragma unroll
                for (int r = 0; r < 4; r++)
                    sm.Ts2[w * 32 + mi * 16 + quad * 4 + r][t * 16 + cl] =
                        (_Float16)(acc[mi][t][r] * scl);
        __syncthreads();
        _Float16* dst = (s == 0) ? qh : kh;
        const int colbase = bn * 64 - s * 384;   // 0..320
        const int b  = (bm * 128) >> 11;
        const int n0 = (bm * 128) & 2047;
        #pragma unroll
        for (int i = 0; i < 4; i++) {
            const int c = i * 256 + tid;         // 0..1023 chunks of 8
            const int row = c >> 3, ch = c & 7;
            const int gcol = colbase + ch * 8;   // multiple of 8; 48=6x8 -> no straddle
            const int head = gcol / 48, d = gcol - head * 48;
            const int bh = b * 8 + head;
            *(f16x8*)&dst[(size_t)(bh * 2048 + n0 + row) * 48 + d] =
                *(const f16x8*)&sm.Ts2[row][ch * 8];
        }
    }
}

// ---------------------------------------------------------------------------
// Flash attention, 32x32x16 f16 MFMA, no-max softmax, reg-prefetch staging.
// Block 256 = 4 waves; 128 queries of one (b,h); 64-key tiles.
// S^T = K.Q^T gives C[key][query]; its C-layout regs are a valid PV B-operand
// under key permutation kappa. PV: O^T = V^T.P^T with V^T staged pre-permuted
// (key slot s=16c+8h+j holds actual key 16c+4h+(j&3)+8(j>>2)). P stays in
// registers. l via ones-row 48 of V^T (-> o1 reg 8, h=0 lanes).
// Epilogue: O^T -> LDS transpose (union) -> coalesced f16x8 stores.
// ---------------------------------------------------------------------------
union AttnSmem {
    struct {
        _Float16 Ks[64][56];    // [key][dh]        7168 B
        _Float16 Vts[64][72];   // [dh][key-slot]   9216 B; row 48 ones, 49-63 zero
    } a;
    _Float16 Ot[128][58];       // epilogue transpose [q][dh] 14848 B
};

__global__ __launch_bounds__(256) void attn_f16(const _Float16* __restrict__ qh,
                                                const _Float16* __restrict__ kh,
                                                const _Float16* __restrict__ vt,
                                                _Float16* __restrict__ ab)
{
    __shared__ AttnSmem sm;
    const int tid = threadIdx.x;
    const int w = tid >> 6, lane = tid & 63, ln = lane & 31, h = lane >> 5;
    const int bh = blockIdx.x, qt = blockIdx.y;

    // one-time: Vts rows 48..63 (48 = ones for l, rest zero) — slot-invariant
    for (int i = tid; i < 16 * 72; i += 256) {
        const int r = 48 + i / 72, c = i - (i / 72) * 72;
        sm.a.Vts[r][c] = (r == 48) ? (_Float16)1.0f : (_Float16)0.0f;
    }

    // Q B-frags (3, dh = 16i + 8h + 0..7), query = qt*128 + w*32 + ln
    f16x8 qf[3];
    {
        const _Float16* qp = qh + (size_t)(bh * 2048 + qt * 128 + w * 32 + ln) * 48 + 8 * h;
        qf[0] = *(const f16x8*)qp;
        qf[1] = *(const f16x8*)(qp + 16);
        qf[2] = *(const f16x8*)(qp + 32);
    }

    f32x16 o0, o1;
    #pragma unroll
    for (int r = 0; r < 16; r++) { o0[r] = 0.f; o1[r] = 0.f; }

    const _Float16* kbase = kh + (size_t)bh * 2048 * 48;
    const _Float16* vbase = vt + (size_t)bh * 48 * 2048;

    // K staging: 512 chunks of 8 (row=c/6, col=(c%6)*8), 2 per thread (2nd if tid<128)
    const int kr0 = tid / 6,         kc0 = (tid % 6) * 8;
    const int kid1 = tid + 256;
    const int kr1 = kid1 / 6,        kc1 = (kid1 % 6) * 8;
    // V staging: 384 chunks of 8 keys (dh row = c>>3, key col = (c&7)*8);
    // permuted LDS slots: c_chunk=(tid&7)>>1, b_key=tid&1 ->
    //   keys t=0..3 -> slots 16*c_chunk + 4*b_key + t ; t=4..7 -> +8
    const int vr0 = tid >> 3,        vc0 = (tid & 7) * 8;
    const int vr1 = (tid + 256) >> 3;
    const int vslot_lo = 16 * ((tid & 7) >> 1) + 4 * (tid & 1);
    const _Float16* ks0 = kbase + (size_t)kr0 * 48 + kc0;
    const _Float16* ks1 = kbase + (size_t)kr1 * 48 + kc1;
    const _Float16* vs0 = vbase + (size_t)vr0 * 2048 + vc0;
    const _Float16* vs1 = vbase + (size_t)vr1 * 2048 + vc0;

    // prefetch tile 0 into registers
    f16x8 rk0 = *(const f16x8*)ks0;
    f16x8 rv0 = *(const f16x8*)vs0;
    f16x8 rk1, rv1;
    if (tid < 128) { rk1 = *(const f16x8*)ks1; rv1 = *(const f16x8*)vs1; }

    for (int kt = 0; kt < 2048; kt += 64) {
        __syncthreads();
        *(f16x8*)&sm.a.Ks[kr0][kc0] = rk0;
        {   // permuted V^T staging: two f16x4 writes
            const f16x4* rvh = (const f16x4*)&rv0;
            *(f16x4*)&sm.a.Vts[vr0][vslot_lo]     = rvh[0];
            *(f16x4*)&sm.a.Vts[vr0][vslot_lo + 8] = rvh[1];
        }
        if (tid < 128) {
            *(f16x8*)&sm.a.Ks[kr1][kc1] = rk1;
            const f16x4* rvh = (const f16x4*)&rv1;
            *(f16x4*)&sm.a.Vts[vr1][vslot_lo]     = rvh[0];
            *(f16x4*)&sm.a.Vts[vr1][vslot_lo + 8] = rvh[1];
        }
        __syncthreads();
        if (kt + 64 < 2048) {        // issue next-tile loads; waited at next write
            rk0 = *(const f16x8*)(ks0 + (size_t)(kt + 64) * 48);
            rv0 = *(const f16x8*)(vs0 + kt + 64);
            if (tid < 128) {
                rk1 = *(const f16x8*)(ks1 + (size_t)(kt + 64) * 48);
                rv1 = *(const f16x8*)(vs1 + kt + 64);
            }
        }

        // ---- S^T = K.Q^T : C[key][query], regs = keys (r&3)+8(r>>2)+4h ----
        f32x16 s0, s1;
        #pragma unroll
        for (int r = 0; r < 16; r++) { s0[r] = 0.f; s1[r] = 0.f; }
        #pragma unroll
        for (int i = 0; i < 3; i++) {
            const f16x8 ka0 = *(const f16x8*)&sm.a.Ks[ln][16 * i + 8 * h];
            s0 = __builtin_amdgcn_mfma_f32_32x32x16_f16(ka0, qf[i], s0, 0, 0, 0);
            const f16x8 ka1 = *(const f16x8*)&sm.a.Ks[32 + ln][16 * i + 8 * h];
            s1 = __builtin_amdgcn_mfma_f32_32x32x16_f16(ka1, qf[i], s1, 0, 0, 0);
        }

        // ---- P = exp2(S^T) packed directly as PV B-frags (no LDS!) ----
        f16x8 pbf[4];
        #pragma unroll
        for (int j = 0; j < 8; j++) {
            pbf[0][j] = (_Float16)exp2f(s0[j]);
            pbf[1][j] = (_Float16)exp2f(s0[8 + j]);
            pbf[2][j] = (_Float16)exp2f(s1[j]);
            pbf[3][j] = (_Float16)exp2f(s1[8 + j]);
        }

        // ---- O^T += V^T.P^T : A = permuted Vts frags, B = pbf ----
        #pragma unroll
        for (int c = 0; c < 4; c++) {
            const f16x8 av0 = *(const f16x8*)&sm.a.Vts[ln][16 * c + 8 * h];
            o0 = __builtin_amdgcn_mfma_f32_32x32x16_f16(av0, pbf[c], o0, 0, 0, 0);
            const f16x8 av1 = *(const f16x8*)&sm.a.Vts[32 + ln][16 * c + 8 * h];
            o1 = __builtin_amdgcn_mfma_f32_32x32x16_f16(av1, pbf[c], o1, 0, 0, 0);
        }
    }

    // ---- l = O^T row 48 = o1 reg 8 on h=0 lanes (their query = ln) ----
    const float lr  = __shfl(o1[8], ln);     // broadcast across h halves
    const float inv = 1.f / lr;

    // ---- epilogue: O^T -> LDS transpose -> coalesced stores ----
    __syncthreads();                         // all Vts/Ks reads done; Ot aliases
    #pragma unroll
    for (int r = 0; r < 16; r++)
        sm.Ot[w * 32 + ln][(r & 3) + 8 * (r >> 2) + 4 * h] = (_Float16)(o0[r] * inv);
    #pragma unroll
    for (int r = 0; r < 8; r++)
        sm.Ot[w * 32 + ln][32 + (r & 3) + 8 * (r >> 2) + 4 * h] = (_Float16)(o1[r] * inv);
    __syncthreads();
    const int b = bh >> 3, hd = bh & 7;
    #pragma unroll
    for (int i = 0; i < 3; i++) {
        const int c2 = i * 256 + tid;        // 0..767 chunks of 8 (128 rows x 6)
        const int row = c2 / 6, ch = c2 % 6;
        const int q = qt * 128 + row;
        *(f16x8*)&ab[(size_t)(b * 2048 + q) * 384 + hd * 48 + ch * 8] =
            *(const f16x8*)&sm.Ot[row][ch * 8];
    }
}

// ---------------------------------------------------------------------------
// Proj GEMM: A = ab[8192][384] f16, Bt = wprojt[384][384] f16, +bias -> fp32
// 64x64 tile, BK=64, padded LDS, reg-prefetch.
// ---------------------------------------------------------------------------
__global__ __launch_bounds__(256) void proj_f16(const _Float16* __restrict__ A,
                                                const _Float16* __restrict__ Bt,
                                                const float* __restrict__ bias,
                                                float* __restrict__ out)
{
    __shared__ _Float16 As[64][72];
    __shared__ _Float16 Bs[64][72];
    const int tid = threadIdx.x;
    const int w = tid >> 6, lane = tid & 63, cl = lane & 15, quad = lane >> 4;
    const int bm = blockIdx.x, bn = blockIdx.y;

    f32x4 acc[4];
    const f32x4 z4 = {0.f, 0.f, 0.f, 0.f};
    #pragma unroll
    for (int t = 0; t < 4; t++) acc[t] = z4;

    const int ar = tid >> 3, ac = (tid & 7) * 8;
    const _Float16* Ag = A  + (size_t)(bm * 64 + ar) * 384 + ac;
    const _Float16* Bg = Bt + (size_t)(bn * 64 + ar) * 384 + ac;

    f16x8 pa[2], pb[2];
    #pragma unroll
    for (int j = 0; j < 2; j++) {
        pa[j] = *(const f16x8*)(Ag + (size_t)(32 * j) * 384);
        pb[j] = *(const f16x8*)(Bg + (size_t)(32 * j) * 384);
    }

    for (int k0 = 0; k0 < 384; k0 += 64) {
        __syncthreads();
        #pragma unroll
        for (int j = 0; j < 2; j++) {
            *(f16x8*)&As[ar + 32 * j][ac] = pa[j];
            *(f16x8*)&Bs[ar + 32 * j][ac] = pb[j];
        }
        __syncthreads();
        if (k0 + 64 < 384) {
            #pragma unroll
            for (int j = 0; j < 2; j++) {
                pa[j] = *(const f16x8*)(Ag + (size_t)(32 * j) * 384 + k0 + 64);
                pb[j] = *(const f16x8*)(Bg + (size_t)(32 * j) * 384 + k0 + 64);
            }
        }
        #pragma unroll
        for (int kh2 = 0; kh2 < 2; kh2++) {
            const f16x8 af = *(const f16x8*)&As[w * 16 + cl][kh2 * 32 + quad * 8];
            #pragma unroll
            for (int t = 0; t < 4; t++) {
                const f16x8 bf = *(const f16x8*)&Bs[t * 16 + cl][kh2 * 32 + quad * 8];
                acc[t] = __builtin_amdgcn_mfma_f32_16x16x32_f16(af, bf, acc[t], 0, 0, 0);
            }
        }
    }

    #pragma unroll
    for (int t = 0; t < 4; t++) {
        const int col = bn * 64 + t * 16 + cl;
        const float bv = bias[col];
        #pragma unroll
        for (int r = 0; r < 4; r++) {
            const int row = bm * 64 + w * 16 + quad * 4 + r;
            out[(size_t)row * 384 + col] = acc[t][r] + bv;
        }
    }
}

// ---------------------------------------------------------------------------
extern "C" void kernel_launch(void* const* d_in, const int* in_sizes, int n_in,
                              void* d_out, int out_size, void* d_ws, size_t ws_size,
                              hipStream_t stream) {
    const float* x     = (const float*)d_in[0];  // [4,2048,384]
    const float* Wqkv  = (const float*)d_in[1];  // [384,1152]
    const float* Wproj = (const float*)d_in[2];  // [384,384]
    const float* bproj = (const float*)d_in[3];  // [384]
    float* out = (float*)d_out;

    char* ws = (char*)d_ws;
    _Float16* wqkvt  = (_Float16*)(ws + 0);          // 1152*384*2 =   884,736
    _Float16* wprojt = (_Float16*)(ws + 884736);     // 384*384*2  =   294,912
    _Float16* qh     = (_Float16*)(ws + 1179648);    // 32*2048*48*2 = 6,291,456
    _Float16* kh     = (_Float16*)(ws + 7471104);    // 6,291,456
    _Float16* vt     = (_Float16*)(ws + 13762560);   // 6,291,456
    _Float16* ab     = (_Float16*)(ws + 20054016);   // 6,291,456
    // total 26,345,472 B

    prep<<<144, 256, 0, stream>>>(Wqkv, Wproj, wqkvt, wprojt);
    qkv_f16<<<dim3(64, 18), 256, 0, stream>>>(x, wqkvt, qh, kh, vt);
    attn_f16<<<dim3(32, 16), 256, 0, stream>>>(qh, kh, vt, ab);
    proj_f16<<<dim3(128, 6), 256, 0, stream>>>(ab, wprojt, bproj, out);
}

// Round 15
// 147.960 us; speedup vs baseline: 1.2986x; 1.0103x over previous
//
#include <hip/hip_runtime.h>
#include <hip/hip_bf16.h>

// Attention B=4,N=2048,D=384,H=8,DH=48 — Round 14:
//  - qkv: 128x128 tile (grid 64x9, BK=32) + f16 x (converted once in prep)
//    -> qkv HBM traffic ~282 MB -> ~112 MB; cvt out of the K-loop.
//  - attn: R13 (register-P via kappa permutation) unchanged.
//  - proj unchanged.

typedef _Float16 f16x8 __attribute__((ext_vector_type(8)));
typedef _Float16 f16x4 __attribute__((ext_vector_type(4)));
typedef float    f32x4 __attribute__((ext_vector_type(4)));
typedef float    f32x16 __attribute__((ext_vector_type(16)));

// scale * log2(e) = 48^-0.5 * 1.4426950408889634
#define QSCL 0.20822035963448658f

// ---------------------------------------------------------------------------
// prep: blocks 0..143 transpose weights (LDS-tiled); 144..399 convert x->f16
// ---------------------------------------------------------------------------
__global__ __launch_bounds__(256) void prep(const float4* __restrict__ x,
                                            const float* __restrict__ wq,
                                            const float* __restrict__ wp,
                                            f16x4* __restrict__ xh4,
                                            _Float16* __restrict__ wqt,
                                            _Float16* __restrict__ wpt)
{
    __shared__ _Float16 t[64][65];
    const int blk = blockIdx.x, tid = threadIdx.x;
    if (blk < 144) {
        const float* src; _Float16* dst; int Nn, k0, n0;
        if (blk < 108) {            // Wqkv: 6 k-tiles x 18 n-tiles
            src = wq; dst = wqt; Nn = 1152;
            k0 = (blk % 6) * 64; n0 = (blk / 6) * 64;
        } else {                    // Wproj: 6 x 6
            const int b2 = blk - 108;
            src = wp; dst = wpt; Nn = 384;
            k0 = (b2 % 6) * 64; n0 = (b2 / 6) * 64;
        }
        #pragma unroll
        for (int i = 0; i < 16; i++) {
            const int id = tid + i * 256;
            const int k = id >> 6, n = id & 63;      // coalesced over n
            t[k][n] = (_Float16)src[(size_t)(k0 + k) * Nn + n0 + n];
        }
        __syncthreads();
        #pragma unroll
        for (int i = 0; i < 16; i++) {
            const int id = tid + i * 256;
            const int n = id >> 6, k = id & 63;      // coalesced over k
            dst[(size_t)(n0 + n) * 384 + k0 + k] = t[k][n];
        }
    } else {
        const int base = (blk - 144) * 3072;         // 256 blocks x 3072 = 786432
        #pragma unroll
        for (int r = 0; r < 12; r++) {
            const int j = base + r * 256 + tid;
            const float4 tt = x[j];
            f16x4 hh;
            hh[0] = (_Float16)tt.x; hh[1] = (_Float16)tt.y;
            hh[2] = (_Float16)tt.z; hh[3] = (_Float16)tt.w;
            xh4[j] = hh;
        }
    }
}

// ---------------------------------------------------------------------------
// QKV GEMM: A = xh[8192][384] f16, Bt = wqkvt[1152][384] f16.
// 128x128 tile, BK=32, padded LDS (stride 40), 16x16x32 MFMA, 4 waves,
// reg-prefetch. Epilogue via LDS transpose -> coalesced f16x8 stores.
// ---------------------------------------------------------------------------
union QkvSmem {
    struct { _Float16 As[128][40]; _Float16 Bs[128][40]; } g;  // 20480 B
    _Float16 Ts[128][136];   // V transpose   [col][n]   34816 B
    _Float16 Ts2[128][136];  // q/k transpose [row][col] 34816 B
};

__global__ __launch_bounds__(256) void qkv_f16(const _Float16* __restrict__ A,
                                               const _Float16* __restrict__ Bt,
                                               _Float16* __restrict__ qh,
                                               _Float16* __restrict__ kh,
                                               _Float16* __restrict__ vt)
{
    __shared__ QkvSmem sm;
    const int tid = threadIdx.x;
    const int w = tid >> 6, lane = tid & 63, cl = lane & 15, quad = lane >> 4;
    const int bm = blockIdx.x, bn = blockIdx.y;

    f32x4 acc[2][8];
    const f32x4 z4 = {0.f, 0.f, 0.f, 0.f};
    #pragma unroll
    for (int mi = 0; mi < 2; mi++)
        #pragma unroll
        for (int t = 0; t < 8; t++) acc[mi][t] = z4;

    const int ar = tid >> 2, ac = (tid & 3) * 8;     // 512 chunks: 2/thread
    const _Float16* Ag = A  + (size_t)(bm * 128 + ar) * 384 + ac;
    const _Float16* Bg = Bt + (size_t)(bn * 128 + ar) * 384 + ac;

    f16x8 pa[2], pb[2];
    #pragma unroll
    for (int j = 0; j < 2; j++) {
        pa[j] = *(const f16x8*)(Ag + (size_t)(64 * j) * 384);
        pb[j] = *(const f16x8*)(Bg + (size_t)(64 * j) * 384);
    }

    for (int k0 = 0; k0 < 384; k0 += 32) {
        __syncthreads();
        #pragma unroll
        for (int j = 0; j < 2; j++) {
            *(f16x8*)&sm.g.As[ar + 64 * j][ac] = pa[j];
            *(f16x8*)&sm.g.Bs[ar + 64 * j][ac] = pb[j];
        }
        __syncthreads();
        if (k0 + 32 < 384) {
            #pragma unroll
            for (int j = 0; j < 2; j++) {
                pa[j] = *(const f16x8*)(Ag + (size_t)(64 * j) * 384 + k0 + 32);
                pb[j] = *(const f16x8*)(Bg + (size_t)(64 * j) * 384 + k0 + 32);
            }
        }
        f16x8 bf[8];
        #pragma unroll
        for (int t = 0; t < 8; t++)
            bf[t] = *(const f16x8*)&sm.g.Bs[t * 16 + cl][quad * 8];
        #pragma unroll
        for (int mi = 0; mi < 2; mi++) {
            const f16x8 af = *(const f16x8*)&sm.g.As[w * 32 + mi * 16 + cl][quad * 8];
            #pragma unroll
            for (int t = 0; t < 8; t++)
                acc[mi][t] = __builtin_amdgcn_mfma_f32_16x16x32_f16(af, bf[t], acc[mi][t], 0, 0, 0);
        }
    }

    const int s = (bn * 128) / 384;    // uniform per block (384 % 128 == 0)
    const int b  = (bm * 128) >> 11;
    const int n0 = (bm * 128) & 2047;
    if (s == 2) {
        // ---- V: LDS transpose [col][n] -> coalesced stores along n ----
        __syncthreads();
        #pragma unroll
        for (int t = 0; t < 8; t++)
            #pragma unroll
            for (int mi = 0; mi < 2; mi++)
                #pragma unroll
                for (int r = 0; r < 4; r++)
                    sm.Ts[t * 16 + cl][w * 32 + mi * 16 + quad * 4 + r] =
                        (_Float16)acc[mi][t][r];
        __syncthreads();
        const int colbase = bn * 128 - 768;      // 0,128,256
        #pragma unroll
        for (int i = 0; i < 8; i++) {
            const int c = i * 256 + tid;         // 0..2047 chunks of 8
            const int col = c >> 4, nc = c & 15;
            const int gcol = colbase + col;
            const int head = gcol / 48, d = gcol - head * 48;
            const int bh = b * 8 + head;
            *(f16x8*)&vt[(size_t)(bh * 48 + d) * 2048 + n0 + nc * 8] =
                *(const f16x8*)&sm.Ts[col][nc * 8];
        }
    } else {
        // ---- q/k: LDS transpose [row][col] -> coalesced f16x8 stores ----
        __syncthreads();
        const float scl = (s == 0) ? QSCL : 1.0f;
        #pragma unroll
        for (int t = 0; t < 8; t++)
            #pragma unroll
            for (int mi = 0; mi < 2; mi++)
                #pragma unroll
                for (int r = 0; r < 4; r++)
                    sm.Ts2[w * 32 + mi * 16 + quad * 4 + r][t * 16 + cl] =
                        (_Float16)(acc[mi][t][r] * scl);
        __syncthreads();
        _Float16* dst = (s == 0) ? qh : kh;
        const int colbase = bn * 128 - s * 384;  // 0,128,256
        #pragma unroll
        for (int i = 0; i < 8; i++) {
            const int c = i * 256 + tid;         // 0..2047 chunks of 8
            const int row = c >> 4, ch = c & 15;
            const int gcol = colbase + ch * 8;   // multiple of 8; 48=6x8 -> no straddle
            const int head = gcol / 48, d = gcol - head * 48;
            const int bh = b * 8 + head;
            *(f16x8*)&dst[(size_t)(bh * 2048 + n0 + row) * 48 + d] =
                *(const f16x8*)&sm.Ts2[row][ch * 8];
        }
    }
}

// ---------------------------------------------------------------------------
// Flash attention (R13): 32x32x16 f16 MFMA, no-max softmax, register-P via
// kappa key-permutation; l via ones-row 48; epilogue LDS transpose.
// ---------------------------------------------------------------------------
union AttnSmem {
    struct {
        _Float16 Ks[64][56];    // [key][dh]        7168 B
        _Float16 Vts[64][72];   // [dh][key-slot]   9216 B; row 48 ones, 49-63 zero
    } a;
    _Float16 Ot[128][58];       // epilogue transpose [q][dh] 14848 B
};

__global__ __launch_bounds__(256) void attn_f16(const _Float16* __restrict__ qh,
                                                const _Float16* __restrict__ kh,
                                                const _Float16* __restrict__ vt,
                                                _Float16* __restrict__ ab)
{
    __shared__ AttnSmem sm;
    const int tid = threadIdx.x;
    const int w = tid >> 6, lane = tid & 63, ln = lane & 31, h = lane >> 5;
    const int bh = blockIdx.x, qt = blockIdx.y;

    // one-time: Vts rows 48..63 (48 = ones for l, rest zero) — slot-invariant
    for (int i = tid; i < 16 * 72; i += 256) {
        const int r = 48 + i / 72, c = i - (i / 72) * 72;
        sm.a.Vts[r][c] = (r == 48) ? (_Float16)1.0f : (_Float16)0.0f;
    }

    // Q B-frags (3, dh = 16i + 8h + 0..7), query = qt*128 + w*32 + ln
    f16x8 qf[3];
    {
        const _Float16* qp = qh + (size_t)(bh * 2048 + qt * 128 + w * 32 + ln) * 48 + 8 * h;
        qf[0] = *(const f16x8*)qp;
        qf[1] = *(const f16x8*)(qp + 16);
        qf[2] = *(const f16x8*)(qp + 32);
    }

    f32x16 o0, o1;
    #pragma unroll
    for (int r = 0; r < 16; r++) { o0[r] = 0.f; o1[r] = 0.f; }

    const _Float16* kbase = kh + (size_t)bh * 2048 * 48;
    const _Float16* vbase = vt + (size_t)bh * 48 * 2048;

    const int kr0 = tid / 6,         kc0 = (tid % 6) * 8;
    const int kid1 = tid + 256;
    const int kr1 = kid1 / 6,        kc1 = (kid1 % 6) * 8;
    const int vr0 = tid >> 3,        vc0 = (tid & 7) * 8;
    const int vr1 = (tid + 256) >> 3;
    const int vslot_lo = 16 * ((tid & 7) >> 1) + 4 * (tid & 1);
    const _Float16* ks0 = kbase + (size_t)kr0 * 48 + kc0;
    const _Float16* ks1 = kbase + (size_t)kr1 * 48 + kc1;
    const _Float16* vs0 = vbase + (size_t)vr0 * 2048 + vc0;
    const _Float16* vs1 = vbase + (size_t)vr1 * 2048 + vc0;

    f16x8 rk0 = *(const f16x8*)ks0;
    f16x8 rv0 = *(const f16x8*)vs0;
    f16x8 rk1, rv1;
    if (tid < 128) { rk1 = *(const f16x8*)ks1; rv1 = *(const f16x8*)vs1; }

    for (int kt = 0; kt < 2048; kt += 64) {
        __syncthreads();
        *(f16x8*)&sm.a.Ks[kr0][kc0] = rk0;
        {
            const f16x4* rvh = (const f16x4*)&rv0;
            *(f16x4*)&sm.a.Vts[vr0][vslot_lo]     = rvh[0];
            *(f16x4*)&sm.a.Vts[vr0][vslot_lo + 8] = rvh[1];
        }
        if (tid < 128) {
            *(f16x8*)&sm.a.Ks[kr1][kc1] = rk1;
            const f16x4* rvh = (const f16x4*)&rv1;
            *(f16x4*)&sm.a.Vts[vr1][vslot_lo]     = rvh[0];
            *(f16x4*)&sm.a.Vts[vr1][vslot_lo + 8] = rvh[1];
        }
        __syncthreads();
        if (kt + 64 < 2048) {
            rk0 = *(const f16x8*)(ks0 + (size_t)(kt + 64) * 48);
            rv0 = *(const f16x8*)(vs0 + kt + 64);
            if (tid < 128) {
                rk1 = *(const f16x8*)(ks1 + (size_t)(kt + 64) * 48);
                rv1 = *(const f16x8*)(vs1 + kt + 64);
            }
        }

        // ---- S^T = K.Q^T : C[key][query], regs = keys (r&3)+8(r>>2)+4h ----
        f32x16 s0, s1;
        #pragma unroll
        for (int r = 0; r < 16; r++) { s0[r] = 0.f; s1[r] = 0.f; }
        #pragma unroll
        for (int i = 0; i < 3; i++) {
            const f16x8 ka0 = *(const f16x8*)&sm.a.Ks[ln][16 * i + 8 * h];
            s0 = __builtin_amdgcn_mfma_f32_32x32x16_f16(ka0, qf[i], s0, 0, 0, 0);
            const f16x8 ka1 = *(const f16x8*)&sm.a.Ks[32 + ln][16 * i + 8 * h];
            s1 = __builtin_amdgcn_mfma_f32_32x32x16_f16(ka1, qf[i], s1, 0, 0, 0);
        }

        // ---- P = exp2(S^T) packed directly as PV B-frags (no LDS) ----
        f16x8 pbf[4];
        #pragma unroll
        for (int j = 0; j < 8; j++) {
            pbf[0][j] = (_Float16)exp2f(s0[j]);
            pbf[1][j] = (_Float16)exp2f(s0[8 + j]);
            pbf[2][j] = (_Float16)exp2f(s1[j]);
            pbf[3][j] = (_Float16)exp2f(s1[8 + j]);
        }

        // ---- O^T += V^T.P^T : A = permuted Vts frags, B = pbf ----
        #pragma unroll
        for (int c = 0; c < 4; c++) {
            const f16x8 av0 = *(const f16x8*)&sm.a.Vts[ln][16 * c + 8 * h];
            o0 = __builtin_amdgcn_mfma_f32_32x32x16_f16(av0, pbf[c], o0, 0, 0, 0);
            const f16x8 av1 = *(const f16x8*)&sm.a.Vts[32 + ln][16 * c + 8 * h];
            o1 = __builtin_amdgcn_mfma_f32_32x32x16_f16(av1, pbf[c], o1, 0, 0, 0);
        }
    }

    // ---- l = O^T row 48 = o1 reg 8 on h=0 lanes (their query = ln) ----
    const float lr  = __shfl(o1[8], ln);
    const float inv = 1.f / lr;

    // ---- epilogue: O^T -> LDS transpose -> coalesced stores ----
    __syncthreads();
    #pragma unroll
    for (int r = 0; r < 16; r++)
        sm.Ot[w * 32 + ln][(r & 3) + 8 * (r >> 2) + 4 * h] = (_Float16)(o0[r] * inv);
    #pragma unroll
    for (int r = 0; r < 8; r++)
        sm.Ot[w * 32 + ln][32 + (r & 3) + 8 * (r >> 2) + 4 * h] = (_Float16)(o1[r] * inv);
    __syncthreads();
    const int b = bh >> 3, hd = bh & 7;
    #pragma unroll
    for (int i = 0; i < 3; i++) {
        const int c2 = i * 256 + tid;
        const int row = c2 / 6, ch = c2 % 6;
        const int q = qt * 128 + row;
        *(f16x8*)&ab[(size_t)(b * 2048 + q) * 384 + hd * 48 + ch * 8] =
            *(const f16x8*)&sm.Ot[row][ch * 8];
    }
}

// ---------------------------------------------------------------------------
// Proj GEMM: A = ab[8192][384] f16, Bt = wprojt[384][384] f16, +bias -> fp32
// 64x64 tile, BK=64, padded LDS, reg-prefetch.
// ---------------------------------------------------------------------------
__global__ __launch_bounds__(256) void proj_f16(const _Float16* __restrict__ A,
                                                const _Float16* __restrict__ Bt,
                                                const float* __restrict__ bias,
                                                float* __restrict__ out)
{
    __shared__ _Float16 As[64][72];
    __shared__ _Float16 Bs[64][72];
    const int tid = threadIdx.x;
    const int w = tid >> 6, lane = tid & 63, cl = lane & 15, quad = lane >> 4;
    const int bm = blockIdx.x, bn = blockIdx.y;

    f32x4 acc[4];
    const f32x4 z4 = {0.f, 0.f, 0.f, 0.f};
    #pragma unroll
    for (int t = 0; t < 4; t++) acc[t] = z4;

    const int ar = tid >> 3, ac = (tid & 7) * 8;
    const _Float16* Ag = A  + (size_t)(bm * 64 + ar) * 384 + ac;
    const _Float16* Bg = Bt + (size_t)(bn * 64 + ar) * 384 + ac;

    f16x8 pa[2], pb[2];
    #pragma unroll
    for (int j = 0; j < 2; j++) {
        pa[j] = *(const f16x8*)(Ag + (size_t)(32 * j) * 384);
        pb[j] = *(const f16x8*)(Bg + (size_t)(32 * j) * 384);
    }

    for (int k0 = 0; k0 < 384; k0 += 64) {
        __syncthreads();
        #pragma unroll
        for (int j = 0; j < 2; j++) {
            *(f16x8*)&As[ar + 32 * j][ac] = pa[j];
            *(f16x8*)&Bs[ar + 32 * j][ac] = pb[j];
        }
        __syncthreads();
        if (k0 + 64 < 384) {
            #pragma unroll
            for (int j = 0; j < 2; j++) {
                pa[j] = *(const f16x8*)(Ag + (size_t)(32 * j) * 384 + k0 + 64);
                pb[j] = *(const f16x8*)(Bg + (size_t)(32 * j) * 384 + k0 + 64);
            }
        }
        #pragma unroll
        for (int kh2 = 0; kh2 < 2; kh2++) {
            const f16x8 af = *(const f16x8*)&As[w * 16 + cl][kh2 * 32 + quad * 8];
            #pragma unroll
            for (int t = 0; t < 4; t++) {
                const f16x8 bf = *(const f16x8*)&Bs[t * 16 + cl][kh2 * 32 + quad * 8];
                acc[t] = __builtin_amdgcn_mfma_f32_16x16x32_f16(af, bf, acc[t], 0, 0, 0);
            }
        }
    }

    #pragma unroll
    for (int t = 0; t < 4; t++) {
        const int col = bn * 64 + t * 16 + cl;
        const float bv = bias[col];
        #pragma unroll
        for (int r = 0; r < 4; r++) {
            const int row = bm * 64 + w * 16 + quad * 4 + r;
            out[(size_t)row * 384 + col] = acc[t][r] + bv;
        }
    }
}

// ---------------------------------------------------------------------------
extern "C" void kernel_launch(void* const* d_in, const int* in_sizes, int n_in,
                              void* d_out, int out_size, void* d_ws, size_t ws_size,
                              hipStream_t stream) {
    const float* x     = (const float*)d_in[0];  // [4,2048,384]
    const float* Wqkv  = (const float*)d_in[1];  // [384,1152]
    const float* Wproj = (const float*)d_in[2];  // [384,384]
    const float* bproj = (const float*)d_in[3];  // [384]
    float* out = (float*)d_out;

    char* ws = (char*)d_ws;
    _Float16* xh     = (_Float16*)(ws + 0);          // 8192*384*2  = 6,291,456
    _Float16* wqkvt  = (_Float16*)(ws + 6291456);    // 1152*384*2  =   884,736
    _Float16* wprojt = (_Float16*)(ws + 7176192);    // 384*384*2   =   294,912
    _Float16* qh     = (_Float16*)(ws + 7471104);    // 32*2048*48*2 = 6,291,456
    _Float16* kh     = (_Float16*)(ws + 13762560);   // 6,291,456
    _Float16* vt     = (_Float16*)(ws + 20054016);   // 6,291,456
    _Float16* ab     = (_Float16*)(ws + 26345472);   // 6,291,456
    // total 32,636,928 B

    prep<<<400, 256, 0, stream>>>((const float4*)x, Wqkv, Wproj,
                                  (f16x4*)xh, wqkvt, wprojt);
    qkv_f16<<<dim3(64, 9), 256, 0, stream>>>(xh, wqkvt, qh, kh, vt);
    attn_f16<<<dim3(32, 16), 256, 0, stream>>>(qh, kh, vt, ab);
    proj_f16<<<dim3(128, 6), 256, 0, stream>>>(ab, wprojt, bproj, out);
}